// Round 7
// baseline (338.270 us; speedup 1.0000x reference)
//
#include <hip/hip_runtime.h>

typedef unsigned short u16;
typedef unsigned int   u32;
typedef unsigned long long u64;
typedef short s16x8 __attribute__((ext_vector_type(8)));   // 8 x bf16 bits (4 VGPRs)
typedef float f32x4 __attribute__((ext_vector_type(4)));   // MFMA accumulator

#define NPTS   16384
#define KNNK   20
#define SLOTS0 24      // s0 stack slots (trigger 16, growth <= 8 => max 23)
#define TRIG0  16
#define NCH    16      // s1x chunks per query
#define CSZ    1024    // candidates per chunk
#define CCAP   20      // survivor cap per (query, chunk)  [E~5, 6.7 sigma]

#define MFMA_BF16 __builtin_amdgcn_mfma_f32_16x16x32_bf16

__device__ __forceinline__ u16 f2bf(float x) {
  u32 u = __builtin_bit_cast(u32, x);
  u32 r = (u + 0x7FFFu + ((u >> 16) & 1u)) >> 16;   // RNE
  return (u16)r;
}
__device__ __forceinline__ float bf2f(u16 b) {
  u32 u = ((u32)b) << 16;
  return __builtin_bit_cast(float, u);
}
// shared screen metric: fully-specified fma tree (identical in s0 and s1x)
__device__ __forceinline__ float dist2(float4 qp, float4 cd) {
  float dot = fmaf(qp.x, cd.x, fmaf(qp.y, cd.y, qp.z * cd.z));
  return fmaf(-2.0f, dot, qp.w + cd.w);
}

// ---------------------------------------------------------------- prep: pos4 = (x,y,z,|p|^2)
__global__ __launch_bounds__(256) void knnconv_prep(const float* __restrict__ pos,
                                                    float4* __restrict__ pos4) {
  int i = blockIdx.x * 256 + threadIdx.x;
  float x = pos[i * 3 + 0], y = pos[i * 3 + 1], z = pos[i * 3 + 2];
  float sq = (x * x + y * y) + z * z;    // f32 screen only; f64 re-rank decides final set
  pos4[i] = make_float4(x, y, z, sq);
}

// ---------------------------------------------------------------- s0: sample threshold
// grid 256 (query-group), block 512 = 8 waves; lane = query. Each wave scans 512
// samples (every 4th candidate), keeps sorted top-20 (plain f32, lazy stack);
// 8-way merge -> exact 20th-smallest sample d2 -> tau (x1.00001 safety).
__global__ __launch_bounds__(512) void knnconv_s0(const float4* __restrict__ pos4,
                                                  float* __restrict__ tau) {
  __shared__ float lds0[SLOTS0 * 512];   // 48KB stacks; aliased as md[8][64][20]
  float* sd = lds0;
  float* md = lds0;
  const int tid  = threadIdx.x;
  const int lane = tid & 63;
  const int wv   = tid >> 6;             // 0..7
  const int qg   = blockIdx.x;
  const int q    = qg * 64 + lane;
  const float4 qp = pos4[q];
  const float INF = __builtin_inff();

  float top[KNNK];
  #pragma unroll
  for (int j = 0; j < KNNK; ++j) top[j] = INF;
  float thrF = INF;
  int cnt = 0;
  const int kbase = wv * 512;            // sample index base

#define FLUSH0()                                                      \
  { _Pragma("unroll 1")                                               \
    for (int e = 0; e < SLOTS0; e += 2) {                             \
      if (!__any(e < cnt)) break;                                     \
      float lo = (e     < cnt) ? sd[e * 512 + tid]       : INF;       \
      float hi = (e + 1 < cnt) ? sd[(e + 1) * 512 + tid] : INF;       \
      float a_ = fminf(lo, hi), b_ = fmaxf(lo, hi);                   \
      lo = a_; hi = b_;                                               \
      _Pragma("unroll")                                               \
      for (int j = 0; j < KNNK; ++j) {                                \
        float t = top[j];                                             \
        float m = fminf(lo, t);                                       \
        float x = fmaxf(lo, t);                                       \
        top[j] = m;                                                   \
        lo = fminf(x, hi);                                            \
        hi = fmaxf(x, hi);                                            \
      }                                                               \
    }                                                                 \
    thrF = top[KNNK - 1];                                             \
    cnt = 0; }

  for (int t0 = 0; t0 < 512; t0 += 8) {
    float4 g[8];
    #pragma unroll
    for (int u = 0; u < 8; ++u) g[u] = pos4[(kbase + t0 + u) * 4];  // every 4th point
    #pragma unroll
    for (int u = 0; u < 8; ++u) {
      float d2 = dist2(qp, g[u]);
      sd[cnt * 512 + tid] = d2;                        // unconditional (slot <= 22 valid)
      cnt += (d2 < thrF) ? 1 : 0;                      // branchless accept
    }
    if (__any(cnt >= TRIG0)) { FLUSH0(); }
  }
  FLUSH0();

  __syncthreads();                       // stacks dead before md alias
  #pragma unroll
  for (int j = 0; j < KNNK; ++j) md[(wv * 64 + lane) * KNNK + j] = top[j];
  __syncthreads();

  if (tid < 64) {                        // 8-way merge, take 20th smallest
    int ql = tid;
    int h0=0,h1=0,h2=0,h3=0,h4=0,h5=0,h6=0,h7=0;
    float last = INF;
    for (int r = 0; r < KNNK; ++r) {     // heads stay <= 19 while r < 20
      float c0 = md[(0*64+ql)*KNNK+h0], c1 = md[(1*64+ql)*KNNK+h1];
      float c2 = md[(2*64+ql)*KNNK+h2], c3 = md[(3*64+ql)*KNNK+h3];
      float c4 = md[(4*64+ql)*KNNK+h4], c5 = md[(5*64+ql)*KNNK+h5];
      float c6 = md[(6*64+ql)*KNNK+h6], c7 = md[(7*64+ql)*KNNK+h7];
      float bv = c0; int bw = 0;
      if (c1 < bv) { bv = c1; bw = 1; }
      if (c2 < bv) { bv = c2; bw = 2; }
      if (c3 < bv) { bv = c3; bw = 3; }
      if (c4 < bv) { bv = c4; bw = 4; }
      if (c5 < bv) { bv = c5; bw = 5; }
      if (c6 < bv) { bv = c6; bw = 6; }
      if (c7 < bv) { bv = c7; bw = 7; }
      last = bv;
      h0 += (bw==0); h1 += (bw==1); h2 += (bw==2); h3 += (bw==3);
      h4 += (bw==4); h5 += (bw==5); h6 += (bw==6); h7 += (bw==7);
    }
    tau[qg * 64 + ql] = last * 1.00001f;   // covers f32-vs-f64 rank flips + 1-ulp drift
  }
}

// ---------------------------------------------------------------- s1x: screen + compact
// grid 1024 = 256 qg x 4 parts; block 4 waves; lane = query; wave chunk = 1024 cands.
// Register-bitmask accept (3 instr/eval tracking, bit pos compile-time); rare
// ctz-extraction writes survivors straight to global. No LDS at all.
__global__ __launch_bounds__(256) void knnconv_s1x(const float4* __restrict__ pos4,
                                                   const float* __restrict__ tau,
                                                   u16* __restrict__ g1,
                                                   u16* __restrict__ gcnt) {
  const int tid  = threadIdx.x;
  const int lane = tid & 63;
  const int wv   = tid >> 6;
  const int qg    = blockIdx.x >> 2;
  const int part  = blockIdx.x & 3;
  const int chunk = part * 4 + wv;       // 0..15
  const int cbase = chunk * CSZ;
  const int q     = qg * 64 + lane;
  const float4 qp = pos4[q];
  const float tq  = tau[q];
  const float4* cp = pos4 + cbase;
  u16* dst = g1 + (q * NCH + chunk) * CCAP;
  int cnt = 0;

  #pragma unroll 1
  for (int sp = 0; sp < CSZ; sp += 64) { // 16 spans of 64 candidates
    u32 mlo = 0, mhi = 0;
    #pragma unroll
    for (int t0 = 0; t0 < 64; t0 += 8) {
      float4 g[8];
      #pragma unroll
      for (int u = 0; u < 8; ++u) g[u] = cp[sp + t0 + u];   // 8 loads in flight
      #pragma unroll
      for (int u = 0; u < 8; ++u) {
        float d2 = dist2(qp, g[u]);
        bool acc = d2 <= tq;
        if (t0 + u < 32) mlo |= acc ? (1u << (t0 + u))      : 0u;
        else             mhi |= acc ? (1u << (t0 + u - 32)) : 0u;
      }
    }
    // rare extraction (E ~0.3 bits/lane/span): divergent ctz loop, global scatter
    int base = cbase + sp;
    while (mlo) {
      int k = __builtin_ctz(mlo); mlo &= mlo - 1;
      if (cnt < CCAP) dst[cnt] = (u16)(base + k);
      ++cnt;
    }
    while (mhi) {
      int k = __builtin_ctz(mhi); mhi &= mhi - 1;
      if (cnt < CCAP) dst[cnt] = (u16)(base + 32 + k);
      ++cnt;
    }
  }
  gcnt[q * NCH + chunk] = (u16)min(cnt, CCAP);
}

// ---------------------------------------------------------------- s2: gather + f64 re-rank
// block = 16 queries x 16 slots; keys[16][256] u64 in LDS; rank-count with runtime T.
__global__ __launch_bounds__(256) void knnconv_s2(const float4* __restrict__ pos4,
                                                  const u16* __restrict__ g1,
                                                  const u16* __restrict__ gcnt,
                                                  int* __restrict__ knn_out) {
  __shared__ u64 keys[16 * 256];         // 32KB
  __shared__ u16 Tq[16];
  const int tid = threadIdx.x;
  const int iq = tid >> 4, s = tid & 15;
  const int q0 = blockIdx.x * 16;
  const int q = q0 + iq;

  #pragma unroll
  for (int i = 0; i < 16; ++i) keys[i * 256 + tid] = ~0ULL;
  __syncthreads();

  int off = 0, T = 0;
  #pragma unroll
  for (int j = 0; j < NCH; ++j) {
    int cj = gcnt[q * NCH + j];
    off += (j < s) ? cj : 0;
    T += cj;
  }
  if (s == 0) Tq[iq] = (u16)min(T, 256);
  int myc = gcnt[q * NCH + s];
  float4 P = pos4[q];
  for (int i = 0; i < myc; ++i) {
    int pos = off + i;
    if (pos >= 256) break;               // deterministic clamp (never hit in practice)
    int cidx = (int)g1[(q * NCH + s) * CCAP + i];
    float4 C = pos4[cidx];
    double qx = P.x, qy = P.y, qz = P.z;
    double cx = C.x, cy = C.y, cz = C.z;
    double sqq = qx * qx + qy * qy + qz * qz;
    double sqc = cx * cx + cy * cy + cz * cz;
    double dot = qx * cx + qy * cy + qz * cz;
    double d   = (sqq + sqc) - 2.0 * dot;              // exact to ~1e-16
    float df = fmaxf((float)d, 0.0f);
    keys[iq * 256 + pos] = ((u64)__builtin_bit_cast(u32, df) << 14) | (u32)cidx;
  }
  __syncthreads();

  #pragma unroll 1
  for (int t = 0; t < 16; ++t) {         // iq2 == t uniform across block
    int j = tid & 255;
    int T2 = Tq[t];
    if (j < T2) {
      u64 kj = keys[t * 256 + j];
      const u64* row = keys + t * 256;
      int r = 0;
      for (int k = 0; k < T2; ++k) r += (row[k] < kj) ? 1 : 0;
      if (r < KNNK)
        knn_out[(q0 + t) * KNNK + r] = (int)(kj & 0x3FFFu);
    }
  }
}

// ---------------------------------------------------------------- W1/W2 -> pre-swizzled bf16 (one-shot)
__global__ __launch_bounds__(256) void knnconv_wprep(const float* __restrict__ W1,
                                                     const float* __restrict__ W2,
                                                     u16* __restrict__ w1bf,
                                                     u16* __restrict__ w2bf) {
  int b = blockIdx.x;
  if (b < 128) {
    int e = b * 256 + threadIdx.x;       // 32768 entries
    int n = e >> 7, kk = e & 127;
    float v;
    if (n < 128) v = W1[(128 + kk) * 128 + n];                              // W1d
    else { int n2 = n - 128; v = W1[kk * 128 + n2] - W1[(128 + kk) * 128 + n2]; }  // W1c-W1d
    w1bf[(n * 256 + ((kk * 2) ^ ((n & 7) << 4))) >> 1] = f2bf(v);
  } else {
    int e = (b - 128) * 256 + threadIdx.x;   // 16384 entries
    int n = e >> 7, kk = e & 127;
    w2bf[(n * 256 + ((kk * 2) ^ ((n & 7) << 4))) >> 1] = f2bf(W2[kk * 128 + n]);
  }
}

// ---------------------------------------------------------------- precompute a = f@W1d (bf16), c = f@(W1c-W1d)+b1 (f32)
__global__ __launch_bounds__(256) void knnconv_prec(const float* __restrict__ feat,
                                                    const u16* __restrict__ w1bf,
                                                    const float* __restrict__ b1,
                                                    u16* __restrict__ a_out,
                                                    float* __restrict__ c_out) {
  __shared__ char sW[65536];   // WT[n=256][k=128] bf16, pre-swizzled (linear copy)
  __shared__ char sF[16384];   // FA[m=64][k=128] bf16, XOR-swizzled
  const int tid = threadIdx.x;
  { // linear coalesced copy of pre-swizzled W1-combined
    const uint4* src = (const uint4*)w1bf;
    uint4* dst = (uint4*)sW;
    #pragma unroll
    for (int r = 0; r < 16; ++r) dst[r * 256 + tid] = src[r * 256 + tid];
  }
  { // stage FA rows (bf16x8 per lane)
    int sub = tid & 15, r0 = tid >> 4;
    int m0 = blockIdx.x * 64;
    for (int rr = 0; rr < 4; ++rr) {
      int r = r0 + rr * 16;
      const float* src = feat + (m0 + r) * 128 + sub * 8;
      float4 v0 = *(const float4*)src;
      float4 v1 = *(const float4*)(src + 4);
      u32 p0 = (u32)f2bf(v0.x) | ((u32)f2bf(v0.y) << 16);
      u32 p1 = (u32)f2bf(v0.z) | ((u32)f2bf(v0.w) << 16);
      u32 p2 = (u32)f2bf(v1.x) | ((u32)f2bf(v1.y) << 16);
      u32 p3 = (u32)f2bf(v1.z) | ((u32)f2bf(v1.w) << 16);
      *(uint4*)(sF + r * 256 + ((sub * 16) ^ ((r & 7) << 4))) = make_uint4(p0, p1, p2, p3);
    }
  }
  __syncthreads();
  const int lane = tid & 63, wv = tid >> 6;
  const int l15 = lane & 15, l4 = lane >> 4;
  f32x4 acc[4][4];
  #pragma unroll
  for (int a = 0; a < 4; ++a)
    #pragma unroll
    for (int b = 0; b < 4; ++b) acc[a][b] = (f32x4){0.f, 0.f, 0.f, 0.f};
  #pragma unroll
  for (int kk = 0; kk < 4; ++kk) {
    int kb = kk * 64 + l4 * 16;
    s16x8 af[4], bfr[4];
    #pragma unroll
    for (int mt = 0; mt < 4; ++mt) {
      int row = mt * 16 + l15;
      af[mt] = *(const s16x8*)(sF + row * 256 + (kb ^ ((row & 7) << 4)));
    }
    #pragma unroll
    for (int nt = 0; nt < 4; ++nt) {
      int n = (wv * 4 + nt) * 16 + l15;
      bfr[nt] = *(const s16x8*)(sW + n * 256 + (kb ^ ((n & 7) << 4)));
    }
    #pragma unroll
    for (int mt = 0; mt < 4; ++mt)
      #pragma unroll
      for (int nt = 0; nt < 4; ++nt)
        acc[mt][nt] = MFMA_BF16(af[mt], bfr[nt], acc[mt][nt], 0, 0, 0);
  }
  int m0 = blockIdx.x * 64;
  #pragma unroll
  for (int nt = 0; nt < 4; ++nt) {
    int n = (wv * 4 + nt) * 16 + l15;
    float bias = (n >= 128) ? b1[n - 128] : 0.0f;
    #pragma unroll
    for (int mt = 0; mt < 4; ++mt)
      #pragma unroll
      for (int r = 0; r < 4; ++r) {
        int m = m0 + mt * 16 + l4 * 4 + r;    // C/D: row=(l>>4)*4+reg, col=l&15
        float v = acc[mt][nt][r];
        if (n < 128) a_out[m * 128 + n] = f2bf(v);
        else         c_out[m * 128 + (n - 128)] = v + bias;
      }
  }
}

// ---------------------------------------------------------------- fused gather + relu + GEMM2 + max
__global__ __launch_bounds__(256) void knnconv_conv(const int* __restrict__ knn,
                                                    const u16* __restrict__ a_in,
                                                    const float* __restrict__ c_in,
                                                    const u16* __restrict__ w2bf,
                                                    const float* __restrict__ b2,
                                                    float* __restrict__ out) {
  __shared__ char lds[77824];     // [0,40960): A / H2  | [40960,73728): W2T | [73728,77824): c rows
  char* sA = lds;
  char* sW = lds + 40960;
  char* sC = lds + 73728;
  const int tid = threadIdx.x;
  const int q0 = blockIdx.x * 8;

  { // stage c rows for the 8 queries
    int row = tid >> 5, ch4 = (tid & 31) * 4;
    *(float4*)(sC + (row * 128 + ch4) * 4) = *(const float4*)(c_in + (q0 + row) * 128 + ch4);
  }
  __syncthreads();
  { // copy pre-swizzled W2 bf16 (linear copy; layout already swizzled)
    const uint4* src = (const uint4*)w2bf;
    uint4* dst = (uint4*)sW;
    #pragma unroll
    for (int r = 0; r < 8; ++r) dst[r * 256 + tid] = src[r * 256 + tid];
  }
  { // stage A: row r = (query il, neighbor ke): relu(a[idx] + c[il]) -> bf16, swizzled
    int sub = tid & 15, rr = tid >> 4;
    for (int p = 0; p < 10; ++p) {
      int r = p * 16 + rr;
      int il = r / 20;
      int ke = r - il * 20;
      int idx = knn[(q0 + il) * KNNK + ke];
      uint4 av = *(const uint4*)(a_in + idx * 128 + sub * 8);
      float4 c0 = *(const float4*)(sC + (il * 128 + sub * 8) * 4);
      float4 c1 = *(const float4*)(sC + (il * 128 + sub * 8 + 4) * 4);
      float h0 = fmaxf(bf2f((u16)(av.x & 0xFFFF)) + c0.x, 0.f);
      float h1 = fmaxf(bf2f((u16)(av.x >> 16))    + c0.y, 0.f);
      float h2 = fmaxf(bf2f((u16)(av.y & 0xFFFF)) + c0.z, 0.f);
      float h3 = fmaxf(bf2f((u16)(av.y >> 16))    + c0.w, 0.f);
      float h4 = fmaxf(bf2f((u16)(av.z & 0xFFFF)) + c1.x, 0.f);
      float h5 = fmaxf(bf2f((u16)(av.z >> 16))    + c1.y, 0.f);
      float h6 = fmaxf(bf2f((u16)(av.w & 0xFFFF)) + c1.z, 0.f);
      float h7 = fmaxf(bf2f((u16)(av.w >> 16))    + c1.w, 0.f);
      u32 p0 = (u32)f2bf(h0) | ((u32)f2bf(h1) << 16);
      u32 p1 = (u32)f2bf(h2) | ((u32)f2bf(h3) << 16);
      u32 p2 = (u32)f2bf(h4) | ((u32)f2bf(h5) << 16);
      u32 p3 = (u32)f2bf(h6) | ((u32)f2bf(h7) << 16);
      *(uint4*)(sA + r * 256 + ((sub * 16) ^ ((r & 7) << 4))) = make_uint4(p0, p1, p2, p3);
    }
  }
  __syncthreads();
  const int lane = tid & 63, wv = tid >> 6;
  const int l15 = lane & 15, l4 = lane >> 4;
  f32x4 acc[10][2];
  #pragma unroll
  for (int mt = 0; mt < 10; ++mt) { acc[mt][0] = (f32x4){0,0,0,0}; acc[mt][1] = (f32x4){0,0,0,0}; }
  #pragma unroll
  for (int kk = 0; kk < 4; ++kk) {
    int kb = kk * 64 + l4 * 16;
    s16x8 b0, b1r;
    { int n = (wv * 2 + 0) * 16 + l15; b0  = *(const s16x8*)(sW + n * 256 + (kb ^ ((n & 7) << 4))); }
    { int n = (wv * 2 + 1) * 16 + l15; b1r = *(const s16x8*)(sW + n * 256 + (kb ^ ((n & 7) << 4))); }
    #pragma unroll
    for (int mt = 0; mt < 10; ++mt) {
      int row = mt * 16 + l15;
      s16x8 a = *(const s16x8*)(sA + row * 256 + (kb ^ ((row & 7) << 4)));
      acc[mt][0] = MFMA_BF16(a, b0,  acc[mt][0], 0, 0, 0);
      acc[mt][1] = MFMA_BF16(a, b1r, acc[mt][1], 0, 0, 0);
    }
  }
  __syncthreads();              // all waves done reading A before H2 overwrite
  #pragma unroll
  for (int mt = 0; mt < 10; ++mt)
    #pragma unroll
    for (int nt = 0; nt < 2; ++nt) {
      int n = (wv * 2 + nt) * 16 + l15;
      #pragma unroll
      for (int r = 0; r < 4; ++r) {
        int row = mt * 16 + l4 * 4 + r;
        *(u16*)(sA + row * 256 + n * 2) = f2bf(acc[mt][nt][r]);  // H2, plain layout
      }
    }
  __syncthreads();
  { // max over 20 neighbors + b2
    int ch = tid & 127, g = tid >> 7;
    float bias = b2[ch];
    for (int pp = 0; pp < 4; ++pp) {
      int qq = pp * 2 + g;
      float mx = -__builtin_inff();
      #pragma unroll
      for (int e = 0; e < KNNK; ++e)
        mx = fmaxf(mx, bf2f(*(const u16*)(sA + (qq * 20 + e) * 256 + ch * 2)));
      out[(q0 + qq) * 128 + ch] = mx + bias;
    }
  }
}

// ---------------------------------------------------------------- launch
extern "C" void kernel_launch(void* const* d_in, const int* in_sizes, int n_in,
                              void* d_out, int out_size, void* d_ws, size_t ws_size,
                              hipStream_t stream) {
  const float* pos  = (const float*)d_in[0];
  const float* feat = (const float*)d_in[1];
  const float* W1   = (const float*)d_in[2];
  const float* b1   = (const float*)d_in[3];
  const float* W2   = (const float*)d_in[4];
  const float* b2   = (const float*)d_in[5];
  float* out = (float*)d_out;
  char* ws = (char*)d_ws;
  // ws layout:
  //  [0,256K)              pos4 (prep..s2)  -> w1bf 64KB + w2bf 32KB (wprep..conv)
  //  [256K,1.5M)           knn_idx (s2..conv)
  //  [1.5M,12.06M)         g1 survivors 16384x16x20 u16 (s1x..s2) -> a_buf/c_buf (prec..conv)
  //  [12.06M,12.58M)       gcnt 16384x16 u16 (s1x..s2)
  //  [12.58M,12.65M)       tau 16384 f32 (s0..s1x)
  float4* pos4  = (float4*)ws;
  u16*    w1bf  = (u16*)ws;
  u16*    w2bf  = (u16*)(ws + 65536);
  int*    knn   = (int*)(ws + 262144);
  u16*    g1    = (u16*)(ws + 1572864);
  u16*    gcnt  = (u16*)(ws + 12058624);
  float*  tau   = (float*)(ws + 12582912);
  u16*    a_buf = (u16*)(ws + 1572864);
  float*  c_buf = (float*)(ws + 5767168);
  if (ws_size < 14155776) return;   // insufficient scratch (would corrupt)

  knnconv_prep<<<64, 256, 0, stream>>>(pos, pos4);
  knnconv_s0<<<256, 512, 0, stream>>>(pos4, tau);
  knnconv_s1x<<<1024, 256, 0, stream>>>(pos4, tau, g1, gcnt);
  knnconv_s2<<<1024, 256, 0, stream>>>(pos4, g1, gcnt, knn);
  knnconv_wprep<<<192, 256, 0, stream>>>(W1, W2, w1bf, w2bf);          // overwrites pos4 (dead)
  knnconv_prec<<<256, 256, 0, stream>>>(feat, w1bf, b1, a_buf, c_buf); // overwrites g1 (dead)
  knnconv_conv<<<2048, 256, 0, stream>>>(knn, a_buf, c_buf, w2bf, b2, out);
}

// Round 8
// 319.619 us; speedup vs baseline: 1.0584x; 1.0584x over previous
//
#include <hip/hip_runtime.h>

typedef unsigned short u16;
typedef unsigned int   u32;
typedef unsigned long long u64;
typedef short s16x8 __attribute__((ext_vector_type(8)));   // 8 x bf16 bits (4 VGPRs)
typedef float f32x4 __attribute__((ext_vector_type(4)));   // MFMA accumulator

#define NPTS   16384
#define KNNK   20
#define SLOTS0 24      // s0 stack slots (trigger 16, growth <= 8 => max 23)
#define TRIG0  16
#define QCAP   256     // per-query survivor capacity (E~80, 19 sigma)

#define MFMA_BF16 __builtin_amdgcn_mfma_f32_16x16x32_bf16

__device__ __forceinline__ u16 f2bf(float x) {
  u32 u = __builtin_bit_cast(u32, x);
  u32 r = (u + 0x7FFFu + ((u >> 16) & 1u)) >> 16;   // RNE
  return (u16)r;
}
__device__ __forceinline__ float bf2f(u16 b) {
  u32 u = ((u32)b) << 16;
  return __builtin_bit_cast(float, u);
}
__device__ __forceinline__ float dist2(float4 qp, float4 cd) {
  float dot = fmaf(qp.x, cd.x, fmaf(qp.y, cd.y, qp.z * cd.z));
  return fmaf(-2.0f, dot, qp.w + cd.w);
}

// ---------------------------------------------------------------- prep: pos4 = (x,y,z,|p|^2)
__global__ __launch_bounds__(256) void knnconv_prep(const float* __restrict__ pos,
                                                    float4* __restrict__ pos4) {
  int i = blockIdx.x * 256 + threadIdx.x;
  float x = pos[i * 3 + 0], y = pos[i * 3 + 1], z = pos[i * 3 + 2];
  float sq = (x * x + y * y) + z * z;    // f32 screen only; f64 re-rank decides final set
  pos4[i] = make_float4(x, y, z, sq);
}

// ---------------------------------------------------------------- s0: sample threshold
// grid 256 (query-group), block 512 = 8 waves; lane = query. Each wave scans 512
// samples (every 4th candidate), keeps sorted top-20 (lazy stack); 8-way merge
// -> exact 20th-smallest sample d2 -> tau (x1.00001). Superset margin is huge:
// sample-20th ~ full-80th, so screen rounding detail is irrelevant.
__global__ __launch_bounds__(512) void knnconv_s0(const float4* __restrict__ pos4,
                                                  float* __restrict__ tau) {
  __shared__ float lds0[SLOTS0 * 512];   // 48KB stacks; aliased as md[8][64][20]
  float* sd = lds0;
  float* md = lds0;
  const int tid  = threadIdx.x;
  const int lane = tid & 63;
  const int wv   = tid >> 6;             // 0..7
  const int qg   = blockIdx.x;
  const int q    = qg * 64 + lane;
  const float4 qp = pos4[q];
  const float INF = __builtin_inff();

  float top[KNNK];
  #pragma unroll
  for (int j = 0; j < KNNK; ++j) top[j] = INF;
  float thrF = INF;
  int cnt = 0;
  const int kbase = wv * 512;            // sample index base

#define FLUSH0()                                                      \
  { _Pragma("unroll 1")                                               \
    for (int e = 0; e < SLOTS0; e += 2) {                             \
      if (!__any(e < cnt)) break;                                     \
      float lo = (e     < cnt) ? sd[e * 512 + tid]       : INF;       \
      float hi = (e + 1 < cnt) ? sd[(e + 1) * 512 + tid] : INF;       \
      float a_ = fminf(lo, hi), b_ = fmaxf(lo, hi);                   \
      lo = a_; hi = b_;                                               \
      _Pragma("unroll")                                               \
      for (int j = 0; j < KNNK; ++j) {                                \
        float t = top[j];                                             \
        float m = fminf(lo, t);                                       \
        float x = fmaxf(lo, t);                                       \
        top[j] = m;                                                   \
        lo = fminf(x, hi);                                            \
        hi = fmaxf(x, hi);                                            \
      }                                                               \
    }                                                                 \
    thrF = top[KNNK - 1];                                             \
    cnt = 0; }

  for (int t0 = 0; t0 < 512; t0 += 8) {
    float4 g[8];
    #pragma unroll
    for (int u = 0; u < 8; ++u) g[u] = pos4[(kbase + t0 + u) * 4];  // every 4th point
    #pragma unroll
    for (int u = 0; u < 8; ++u) {
      float d2 = dist2(qp, g[u]);
      sd[cnt * 512 + tid] = d2;                        // unconditional (slot <= 22 valid)
      cnt += (d2 < thrF) ? 1 : 0;                      // branchless accept
    }
    if (__any(cnt >= TRIG0)) { FLUSH0(); }
  }
  FLUSH0();

  __syncthreads();                       // stacks dead before md alias
  #pragma unroll
  for (int j = 0; j < KNNK; ++j) md[(wv * 64 + lane) * KNNK + j] = top[j];
  __syncthreads();

  if (tid < 64) {                        // 8-way merge, take 20th smallest
    int ql = tid;
    int h0=0,h1=0,h2=0,h3=0,h4=0,h5=0,h6=0,h7=0;
    float last = INF;
    for (int r = 0; r < KNNK; ++r) {     // heads stay <= 19 while r < 20
      float c0 = md[(0*64+ql)*KNNK+h0], c1 = md[(1*64+ql)*KNNK+h1];
      float c2 = md[(2*64+ql)*KNNK+h2], c3 = md[(3*64+ql)*KNNK+h3];
      float c4 = md[(4*64+ql)*KNNK+h4], c5 = md[(5*64+ql)*KNNK+h5];
      float c6 = md[(6*64+ql)*KNNK+h6], c7 = md[(7*64+ql)*KNNK+h7];
      float bv = c0; int bw = 0;
      if (c1 < bv) { bv = c1; bw = 1; }
      if (c2 < bv) { bv = c2; bw = 2; }
      if (c3 < bv) { bv = c3; bw = 3; }
      if (c4 < bv) { bv = c4; bw = 4; }
      if (c5 < bv) { bv = c5; bw = 5; }
      if (c6 < bv) { bv = c6; bw = 6; }
      if (c7 < bv) { bv = c7; bw = 7; }
      last = bv;
      h0 += (bw==0); h1 += (bw==1); h2 += (bw==2); h3 += (bw==3);
      h4 += (bw==4); h5 += (bw==5); h6 += (bw==6); h7 += (bw==7);
    }
    tau[qg * 64 + ql] = last * 1.00001f;
  }
}

// ---------------------------------------------------------------- s1x: transposed screen
// grid 2048 = 256 qg x 8 parts; block 4 waves; LANE = CANDIDATE (coalesced load,
// lives in registers); 64 queries broadcast from LDS. Accept algebra folded:
// d2<=tau  <=>  0.5*cw - dot <= 0.5*(tau - qw) = tau''.  No VMEM in inner loop.
// Survivors: wave-aggregated atomicAdd on the (uniform) query counter + coalesced
// u16 store. Order in g1 is atomic-order; s2's full rank-sort makes output
// order-invariant, so d_out stays deterministic.
__global__ __launch_bounds__(256, 8) void knnconv_s1x(const float4* __restrict__ pos4,
                                                      const float* __restrict__ tau,
                                                      u16* __restrict__ g1,
                                                      u32* __restrict__ cnt32) {
  __shared__ float4 sQ[64];              // (qx,qy,qz,tau'')
  const int tid  = threadIdx.x;
  const int lane = tid & 63;
  const int wv   = tid >> 6;
  const int qg   = blockIdx.x >> 3;
  const int part = blockIdx.x & 7;

  if (tid < 64) {
    float4 P = pos4[qg * 64 + tid];
    float tq = tau[qg * 64 + tid];
    sQ[tid] = make_float4(P.x, P.y, P.z, 0.5f * (tq - P.w));
  }
  __syncthreads();

  const int cbase = part * 2048 + wv * 512;
  #pragma unroll 1
  for (int t = 0; t < 8; ++t) {
    const int cand = cbase + t * 64 + lane;
    const float4 C = pos4[cand];
    const float cw2 = 0.5f * C.w;
    #pragma unroll 4
    for (int j = 0; j < 64; ++j) {
      float4 Q = sQ[j];                  // uniform LDS broadcast
      float dot = fmaf(Q.x, C.x, fmaf(Q.y, C.y, Q.z * C.z));
      float lhs = cw2 - dot;
      if (lhs <= Q.w) {                  // rare (p ~ 0.5%)
        int qj = qg * 64 + j;            // uniform -> aggregated atomic
        u32 slot = atomicAdd(&cnt32[qj], 1u);
        if (slot < QCAP) g1[(qj << 8) + slot] = (u16)cand;
      }
    }
  }
}

// ---------------------------------------------------------------- s2: gather + f64 re-rank
// block = 16 queries x 16 slots; flat survivor lists; rank-count with runtime T.
__global__ __launch_bounds__(256) void knnconv_s2(const float4* __restrict__ pos4,
                                                  const u16* __restrict__ g1,
                                                  const u32* __restrict__ cnt32,
                                                  int* __restrict__ knn_out) {
  __shared__ u64 keys[16 * 256];         // 32KB
  __shared__ int Tq[16];
  const int tid = threadIdx.x;
  const int iq = tid >> 4, s = tid & 15;
  const int q0 = blockIdx.x * 16;
  const int q = q0 + iq;

  #pragma unroll
  for (int i = 0; i < 16; ++i) keys[i * 256 + tid] = ~0ULL;
  __syncthreads();

  int cnt = min((int)cnt32[q], QCAP);
  if (s == 0) Tq[iq] = cnt;
  float4 P = pos4[q];
  for (int i = s; i < cnt; i += 16) {
    int cidx = (int)g1[(q << 8) + i];
    float4 C = pos4[cidx];
    double qx = P.x, qy = P.y, qz = P.z;
    double cx = C.x, cy = C.y, cz = C.z;
    double sqq = qx * qx + qy * qy + qz * qz;
    double sqc = cx * cx + cy * cy + cz * cz;
    double dot = qx * cx + qy * cy + qz * cz;
    double d   = (sqq + sqc) - 2.0 * dot;              // exact to ~1e-16
    float df = fmaxf((float)d, 0.0f);
    keys[iq * 256 + i] = ((u64)__builtin_bit_cast(u32, df) << 14) | (u32)cidx;
  }
  __syncthreads();

  #pragma unroll 1
  for (int t = 0; t < 16; ++t) {         // uniform per block iteration
    int j = tid & 255;
    int T2 = Tq[t];
    if (j < T2) {
      u64 kj = keys[t * 256 + j];
      const u64* row = keys + t * 256;
      int r = 0;
      for (int k = 0; k < T2; ++k) r += (row[k] < kj) ? 1 : 0;
      if (r < KNNK)
        knn_out[(q0 + t) * KNNK + r] = (int)(kj & 0x3FFFu);
    }
  }
}

// ---------------------------------------------------------------- W1/W2 -> pre-swizzled bf16 (one-shot)
__global__ __launch_bounds__(256) void knnconv_wprep(const float* __restrict__ W1,
                                                     const float* __restrict__ W2,
                                                     u16* __restrict__ w1bf,
                                                     u16* __restrict__ w2bf) {
  int b = blockIdx.x;
  if (b < 128) {
    int e = b * 256 + threadIdx.x;       // 32768 entries
    int n = e >> 7, kk = e & 127;
    float v;
    if (n < 128) v = W1[(128 + kk) * 128 + n];                              // W1d
    else { int n2 = n - 128; v = W1[kk * 128 + n2] - W1[(128 + kk) * 128 + n2]; }  // W1c-W1d
    w1bf[(n * 256 + ((kk * 2) ^ ((n & 7) << 4))) >> 1] = f2bf(v);
  } else {
    int e = (b - 128) * 256 + threadIdx.x;   // 16384 entries
    int n = e >> 7, kk = e & 127;
    w2bf[(n * 256 + ((kk * 2) ^ ((n & 7) << 4))) >> 1] = f2bf(W2[kk * 128 + n]);
  }
}

// ---------------------------------------------------------------- precompute a = f@W1d (bf16), c = f@(W1c-W1d)+b1 (f32)
__global__ __launch_bounds__(256) void knnconv_prec(const float* __restrict__ feat,
                                                    const u16* __restrict__ w1bf,
                                                    const float* __restrict__ b1,
                                                    u16* __restrict__ a_out,
                                                    float* __restrict__ c_out) {
  __shared__ char sW[65536];   // WT[n=256][k=128] bf16, pre-swizzled (linear copy)
  __shared__ char sF[16384];   // FA[m=64][k=128] bf16, XOR-swizzled
  const int tid = threadIdx.x;
  { // linear coalesced copy of pre-swizzled W1-combined
    const uint4* src = (const uint4*)w1bf;
    uint4* dst = (uint4*)sW;
    #pragma unroll
    for (int r = 0; r < 16; ++r) dst[r * 256 + tid] = src[r * 256 + tid];
  }
  { // stage FA rows (bf16x8 per lane)
    int sub = tid & 15, r0 = tid >> 4;
    int m0 = blockIdx.x * 64;
    for (int rr = 0; rr < 4; ++rr) {
      int r = r0 + rr * 16;
      const float* src = feat + (m0 + r) * 128 + sub * 8;
      float4 v0 = *(const float4*)src;
      float4 v1 = *(const float4*)(src + 4);
      u32 p0 = (u32)f2bf(v0.x) | ((u32)f2bf(v0.y) << 16);
      u32 p1 = (u32)f2bf(v0.z) | ((u32)f2bf(v0.w) << 16);
      u32 p2 = (u32)f2bf(v1.x) | ((u32)f2bf(v1.y) << 16);
      u32 p3 = (u32)f2bf(v1.z) | ((u32)f2bf(v1.w) << 16);
      *(uint4*)(sF + r * 256 + ((sub * 16) ^ ((r & 7) << 4))) = make_uint4(p0, p1, p2, p3);
    }
  }
  __syncthreads();
  const int lane = tid & 63, wv = tid >> 6;
  const int l15 = lane & 15, l4 = lane >> 4;
  f32x4 acc[4][4];
  #pragma unroll
  for (int a = 0; a < 4; ++a)
    #pragma unroll
    for (int b = 0; b < 4; ++b) acc[a][b] = (f32x4){0.f, 0.f, 0.f, 0.f};
  #pragma unroll
  for (int kk = 0; kk < 4; ++kk) {
    int kb = kk * 64 + l4 * 16;
    s16x8 af[4], bfr[4];
    #pragma unroll
    for (int mt = 0; mt < 4; ++mt) {
      int row = mt * 16 + l15;
      af[mt] = *(const s16x8*)(sF + row * 256 + (kb ^ ((row & 7) << 4)));
    }
    #pragma unroll
    for (int nt = 0; nt < 4; ++nt) {
      int n = (wv * 4 + nt) * 16 + l15;
      bfr[nt] = *(const s16x8*)(sW + n * 256 + (kb ^ ((n & 7) << 4)));
    }
    #pragma unroll
    for (int mt = 0; mt < 4; ++mt)
      #pragma unroll
      for (int nt = 0; nt < 4; ++nt)
        acc[mt][nt] = MFMA_BF16(af[mt], bfr[nt], acc[mt][nt], 0, 0, 0);
  }
  int m0 = blockIdx.x * 64;
  #pragma unroll
  for (int nt = 0; nt < 4; ++nt) {
    int n = (wv * 4 + nt) * 16 + l15;
    float bias = (n >= 128) ? b1[n - 128] : 0.0f;
    #pragma unroll
    for (int mt = 0; mt < 4; ++mt)
      #pragma unroll
      for (int r = 0; r < 4; ++r) {
        int m = m0 + mt * 16 + l4 * 4 + r;    // C/D: row=(l>>4)*4+reg, col=l&15
        float v = acc[mt][nt][r];
        if (n < 128) a_out[m * 128 + n] = f2bf(v);
        else         c_out[m * 128 + (n - 128)] = v + bias;
      }
  }
}

// ---------------------------------------------------------------- fused gather + relu + GEMM2 + max
__global__ __launch_bounds__(256) void knnconv_conv(const int* __restrict__ knn,
                                                    const u16* __restrict__ a_in,
                                                    const float* __restrict__ c_in,
                                                    const u16* __restrict__ w2bf,
                                                    const float* __restrict__ b2,
                                                    float* __restrict__ out) {
  __shared__ char lds[77824];     // [0,40960): A / H2  | [40960,73728): W2T | [73728,77824): c rows
  char* sA = lds;
  char* sW = lds + 40960;
  char* sC = lds + 73728;
  const int tid = threadIdx.x;
  const int q0 = blockIdx.x * 8;

  { // stage c rows for the 8 queries
    int row = tid >> 5, ch4 = (tid & 31) * 4;
    *(float4*)(sC + (row * 128 + ch4) * 4) = *(const float4*)(c_in + (q0 + row) * 128 + ch4);
  }
  __syncthreads();
  { // copy pre-swizzled W2 bf16 (linear copy; layout already swizzled)
    const uint4* src = (const uint4*)w2bf;
    uint4* dst = (uint4*)sW;
    #pragma unroll
    for (int r = 0; r < 8; ++r) dst[r * 256 + tid] = src[r * 256 + tid];
  }
  { // stage A: row r = (query il, neighbor ke): relu(a[idx] + c[il]) -> bf16, swizzled
    int sub = tid & 15, rr = tid >> 4;
    for (int p = 0; p < 10; ++p) {
      int r = p * 16 + rr;
      int il = r / 20;
      int ke = r - il * 20;
      int idx = knn[(q0 + il) * KNNK + ke];
      uint4 av = *(const uint4*)(a_in + idx * 128 + sub * 8);
      float4 c0 = *(const float4*)(sC + (il * 128 + sub * 8) * 4);
      float4 c1 = *(const float4*)(sC + (il * 128 + sub * 8 + 4) * 4);
      float h0 = fmaxf(bf2f((u16)(av.x & 0xFFFF)) + c0.x, 0.f);
      float h1 = fmaxf(bf2f((u16)(av.x >> 16))    + c0.y, 0.f);
      float h2 = fmaxf(bf2f((u16)(av.y & 0xFFFF)) + c0.z, 0.f);
      float h3 = fmaxf(bf2f((u16)(av.y >> 16))    + c0.w, 0.f);
      float h4 = fmaxf(bf2f((u16)(av.z & 0xFFFF)) + c1.x, 0.f);
      float h5 = fmaxf(bf2f((u16)(av.z >> 16))    + c1.y, 0.f);
      float h6 = fmaxf(bf2f((u16)(av.w & 0xFFFF)) + c1.z, 0.f);
      float h7 = fmaxf(bf2f((u16)(av.w >> 16))    + c1.w, 0.f);
      u32 p0 = (u32)f2bf(h0) | ((u32)f2bf(h1) << 16);
      u32 p1 = (u32)f2bf(h2) | ((u32)f2bf(h3) << 16);
      u32 p2 = (u32)f2bf(h4) | ((u32)f2bf(h5) << 16);
      u32 p3 = (u32)f2bf(h6) | ((u32)f2bf(h7) << 16);
      *(uint4*)(sA + r * 256 + ((sub * 16) ^ ((r & 7) << 4))) = make_uint4(p0, p1, p2, p3);
    }
  }
  __syncthreads();
  const int lane = tid & 63, wv = tid >> 6;
  const int l15 = lane & 15, l4 = lane >> 4;
  f32x4 acc[10][2];
  #pragma unroll
  for (int mt = 0; mt < 10; ++mt) { acc[mt][0] = (f32x4){0,0,0,0}; acc[mt][1] = (f32x4){0,0,0,0}; }
  #pragma unroll
  for (int kk = 0; kk < 4; ++kk) {
    int kb = kk * 64 + l4 * 16;
    s16x8 b0, b1r;
    { int n = (wv * 2 + 0) * 16 + l15; b0  = *(const s16x8*)(sW + n * 256 + (kb ^ ((n & 7) << 4))); }
    { int n = (wv * 2 + 1) * 16 + l15; b1r = *(const s16x8*)(sW + n * 256 + (kb ^ ((n & 7) << 4))); }
    #pragma unroll
    for (int mt = 0; mt < 10; ++mt) {
      int row = mt * 16 + l15;
      s16x8 a = *(const s16x8*)(sA + row * 256 + (kb ^ ((row & 7) << 4)));
      acc[mt][0] = MFMA_BF16(a, b0,  acc[mt][0], 0, 0, 0);
      acc[mt][1] = MFMA_BF16(a, b1r, acc[mt][1], 0, 0, 0);
    }
  }
  __syncthreads();              // all waves done reading A before H2 overwrite
  #pragma unroll
  for (int mt = 0; mt < 10; ++mt)
    #pragma unroll
    for (int nt = 0; nt < 2; ++nt) {
      int n = (wv * 2 + nt) * 16 + l15;
      #pragma unroll
      for (int r = 0; r < 4; ++r) {
        int row = mt * 16 + l4 * 4 + r;
        *(u16*)(sA + row * 256 + n * 2) = f2bf(acc[mt][nt][r]);  // H2, plain layout
      }
    }
  __syncthreads();
  { // max over 20 neighbors + b2
    int ch = tid & 127, g = tid >> 7;
    float bias = b2[ch];
    for (int pp = 0; pp < 4; ++pp) {
      int qq = pp * 2 + g;
      float mx = -__builtin_inff();
      #pragma unroll
      for (int e = 0; e < KNNK; ++e)
        mx = fmaxf(mx, bf2f(*(const u16*)(sA + (qq * 20 + e) * 256 + ch * 2)));
      out[(q0 + qq) * 128 + ch] = mx + bias;
    }
  }
}

// ---------------------------------------------------------------- launch
extern "C" void kernel_launch(void* const* d_in, const int* in_sizes, int n_in,
                              void* d_out, int out_size, void* d_ws, size_t ws_size,
                              hipStream_t stream) {
  const float* pos  = (const float*)d_in[0];
  const float* feat = (const float*)d_in[1];
  const float* W1   = (const float*)d_in[2];
  const float* b1   = (const float*)d_in[3];
  const float* W2   = (const float*)d_in[4];
  const float* b2   = (const float*)d_in[5];
  float* out = (float*)d_out;
  char* ws = (char*)d_ws;
  // ws layout:
  //  [0,256K)              pos4 (prep..s2)  -> w1bf 64KB + w2bf 32KB (wprep..conv)
  //  [256K,1.5M)           knn_idx (s2..conv)
  //  [1.5M,9.9M)           g1 flat survivors 16384x256 u16 (s1x..s2) -> a_buf/c_buf (prec..conv)
  //  [12.06M,12.12M)       cnt32 16384 u32 (memset each launch; s1x..s2)
  //  [12.58M,12.65M)       tau 16384 f32 (s0..s1x)
  float4* pos4  = (float4*)ws;
  u16*    w1bf  = (u16*)ws;
  u16*    w2bf  = (u16*)(ws + 65536);
  int*    knn   = (int*)(ws + 262144);
  u16*    g1    = (u16*)(ws + 1572864);
  u32*    cnt32 = (u32*)(ws + 12058624);
  float*  tau   = (float*)(ws + 12582912);
  u16*    a_buf = (u16*)(ws + 1572864);
  float*  c_buf = (float*)(ws + 5767168);
  if (ws_size < 14155776) return;   // insufficient scratch (would corrupt)

  hipMemsetAsync(cnt32, 0, NPTS * sizeof(u32), stream);   // zero survivor counters
  knnconv_prep<<<64, 256, 0, stream>>>(pos, pos4);
  knnconv_s0<<<256, 512, 0, stream>>>(pos4, tau);
  knnconv_s1x<<<2048, 256, 0, stream>>>(pos4, tau, g1, cnt32);
  knnconv_s2<<<1024, 256, 0, stream>>>(pos4, g1, cnt32, knn);
  knnconv_wprep<<<192, 256, 0, stream>>>(W1, W2, w1bf, w2bf);          // overwrites pos4 (dead)
  knnconv_prec<<<256, 256, 0, stream>>>(feat, w1bf, b1, a_buf, c_buf); // overwrites g1 (dead)
  knnconv_conv<<<2048, 256, 0, stream>>>(knn, a_buf, c_buf, w2bf, b2, out);
}

// Round 11
// 271.470 us; speedup vs baseline: 1.2461x; 1.1774x over previous
//
#include <hip/hip_runtime.h>

typedef unsigned short u16;
typedef unsigned int   u32;
typedef unsigned long long u64;
typedef short s16x8 __attribute__((ext_vector_type(8)));   // 8 x bf16 bits (4 VGPRs)
typedef float f32x4 __attribute__((ext_vector_type(4)));   // MFMA accumulator

#define NPTS   16384
#define KNNK   20
#define SLOTS0 24      // s0 stack slots (trigger 16, growth <= 8 => max 23)
#define TRIG0  16
#define NSEG   16      // s1x candidate parts per query
#define PSZ    1024    // candidates per part
#define SCAP   24      // survivor cap per (query, part)  [E~5; P(overflow) ~1e-4 total]

#define MFMA_BF16 __builtin_amdgcn_mfma_f32_16x16x32_bf16

__device__ __forceinline__ u16 f2bf(float x) {
  u32 u = __builtin_bit_cast(u32, x);
  u32 r = (u + 0x7FFFu + ((u >> 16) & 1u)) >> 16;   // RNE
  return (u16)r;
}
__device__ __forceinline__ float bf2f(u16 b) {
  u32 u = ((u32)b) << 16;
  return __builtin_bit_cast(float, u);
}
__device__ __forceinline__ float dist2(float4 qp, float4 cd) {
  float dot = fmaf(qp.x, cd.x, fmaf(qp.y, cd.y, qp.z * cd.z));
  return fmaf(-2.0f, dot, qp.w + cd.w);
}

// ---------------------------------------------------------------- prep: pos4 = (x,y,z,|p|^2)
__global__ __launch_bounds__(256) void knnconv_prep(const float* __restrict__ pos,
                                                    float4* __restrict__ pos4) {
  int i = blockIdx.x * 256 + threadIdx.x;
  float x = pos[i * 3 + 0], y = pos[i * 3 + 1], z = pos[i * 3 + 2];
  float sq = (x * x + y * y) + z * z;    // f32 screen only; f64 re-rank decides final set
  pos4[i] = make_float4(x, y, z, sq);
}

// ---------------------------------------------------------------- s0: sample threshold
// grid 256 (query-group), block 512 = 8 waves; lane = query. Each wave scans 512
// samples (every 4th candidate), keeps sorted top-20 (lazy stack); 8-way merge
// -> exact 20th-smallest sample d2 -> tau (x1.00001). tau is a provable upper
// bound on the true 20th distance (subset 20th >= full 20th).
__global__ __launch_bounds__(512) void knnconv_s0(const float4* __restrict__ pos4,
                                                  float* __restrict__ tau) {
  __shared__ float lds0[SLOTS0 * 512];   // 48KB stacks; aliased as md[8][64][20]
  float* sd = lds0;
  float* md = lds0;
  const int tid  = threadIdx.x;
  const int lane = tid & 63;
  const int wv   = __builtin_amdgcn_readfirstlane(tid >> 6);   // uniform in SGPR
  const int qg   = blockIdx.x;
  const int q    = qg * 64 + lane;
  const float4 qp = pos4[q];
  const float INF = __builtin_inff();

  float top[KNNK];
  #pragma unroll
  for (int j = 0; j < KNNK; ++j) top[j] = INF;
  float thrF = INF;
  int cnt = 0;
  const int kbase = wv * 512;            // sample index base

#define FLUSH0()                                                      \
  { _Pragma("unroll 1")                                               \
    for (int e = 0; e < SLOTS0; e += 2) {                             \
      if (!__any(e < cnt)) break;                                     \
      float lo = (e     < cnt) ? sd[e * 512 + tid]       : INF;       \
      float hi = (e + 1 < cnt) ? sd[(e + 1) * 512 + tid] : INF;       \
      float a_ = fminf(lo, hi), b_ = fmaxf(lo, hi);                   \
      lo = a_; hi = b_;                                               \
      _Pragma("unroll")                                               \
      for (int j = 0; j < KNNK; ++j) {                                \
        float t = top[j];                                             \
        float m = fminf(lo, t);                                       \
        float x = fmaxf(lo, t);                                       \
        top[j] = m;                                                   \
        lo = fminf(x, hi);                                            \
        hi = fmaxf(x, hi);                                            \
      }                                                               \
    }                                                                 \
    thrF = top[KNNK - 1];                                             \
    cnt = 0; }

  for (int t0 = 0; t0 < 512; t0 += 8) {
    float4 g[8];
    #pragma unroll
    for (int u = 0; u < 8; ++u) g[u] = pos4[(kbase + t0 + u) * 4];  // every 4th point (uniform)
    #pragma unroll
    for (int u = 0; u < 8; ++u) {
      float d2 = dist2(qp, g[u]);
      sd[cnt * 512 + tid] = d2;                        // unconditional (slot <= 22 valid)
      cnt += (d2 < thrF) ? 1 : 0;                      // branchless accept
    }
    if (__any(cnt >= TRIG0)) { FLUSH0(); }
  }
  FLUSH0();

  __syncthreads();                       // stacks dead before md alias
  #pragma unroll
  for (int j = 0; j < KNNK; ++j) md[(wv * 64 + lane) * KNNK + j] = top[j];
  __syncthreads();

  if (tid < 64) {                        // 8-way merge, take 20th smallest
    int ql = tid;
    int h0=0,h1=0,h2=0,h3=0,h4=0,h5=0,h6=0,h7=0;
    float last = INF;
    for (int r = 0; r < KNNK; ++r) {     // heads stay <= 19 while r < 20
      float c0 = md[(0*64+ql)*KNNK+h0], c1 = md[(1*64+ql)*KNNK+h1];
      float c2 = md[(2*64+ql)*KNNK+h2], c3 = md[(3*64+ql)*KNNK+h3];
      float c4 = md[(4*64+ql)*KNNK+h4], c5 = md[(5*64+ql)*KNNK+h5];
      float c6 = md[(6*64+ql)*KNNK+h6], c7 = md[(7*64+ql)*KNNK+h7];
      float bv = c0; int bw = 0;
      if (c1 < bv) { bv = c1; bw = 1; }
      if (c2 < bv) { bv = c2; bw = 2; }
      if (c3 < bv) { bv = c3; bw = 3; }
      if (c4 < bv) { bv = c4; bw = 4; }
      if (c5 < bv) { bv = c5; bw = 5; }
      if (c6 < bv) { bv = c6; bw = 6; }
      if (c7 < bv) { bv = c7; bw = 7; }
      last = bv;
      h0 += (bw==0); h1 += (bw==1); h2 += (bw==2); h3 += (bw==3);
      h4 += (bw==4); h5 += (bw==5); h6 += (bw==6); h7 += (bw==7);
    }
    tau[qg * 64 + ql] = last * 1.00001f;
  }
}

// ---------------------------------------------------------------- s1x: scalar-broadcast screen
// grid 1024 = 256 qg x 4 part-blocks; block 4 waves; wave -> part = pb*4+wv.
// LANE = QUERY (Q + tau'' + survivor COUNTER all in registers); candidates via
// wave-uniform scalar loads (s_load). Accept: fmaf(0.5,cw,-dot) <= Qt.
// Survivors -> private per-(q,part) global segment: no atomics, no LDS.
// Segment order = ascending candidate idx; s2's rank-sort makes output
// order-invariant -> deterministic.
__global__ __launch_bounds__(256) void knnconv_s1x(const float4* __restrict__ pos4,
                                                   const float* __restrict__ tau,
                                                   u16* __restrict__ g1,
                                                   u16* __restrict__ gcnt) {
  const int tid  = threadIdx.x;
  const int lane = tid & 63;
  const int wv   = __builtin_amdgcn_readfirstlane(tid >> 6);   // uniform -> SGPR
  const int qg   = blockIdx.x >> 2;
  const int pb   = blockIdx.x & 3;
  const int part = pb * 4 + wv;          // 0..15, one wave owns one part
  const int q    = qg * 64 + lane;
  const float4 P = pos4[q];
  const float Qx = P.x, Qy = P.y, Qz = P.z;
  const float Qt = 0.5f * (tau[q] - P.w);
  const int cbase = part * PSZ;
  const float4* cp = pos4 + cbase;       // SGPR base -> s_load candidates
  u16* seg = g1 + (q * NSEG + part) * SCAP;
  int cnt = 0;

  #pragma unroll 1
  for (int t0 = 0; t0 < PSZ; t0 += 8) {
    float4 c[8];
    #pragma unroll
    for (int u = 0; u < 8; ++u) c[u] = cp[t0 + u];     // wave-uniform scalar loads
    #pragma unroll
    for (int u = 0; u < 8; ++u) {
      float dot = fmaf(Qx, c[u].x, fmaf(Qy, c[u].y, Qz * c[u].z));
      float lhs = fmaf(0.5f, c[u].w, -dot);            // 0.5*cw - dot
      if (lhs <= Qt) {                                 // rare (p ~ 0.5% per lane)
        if (cnt < SCAP) seg[cnt] = (u16)(cbase + t0 + u);
        ++cnt;
      }
    }
  }
  gcnt[q * NSEG + part] = (u16)min(cnt, SCAP);
}

// ---------------------------------------------------------------- s2: gather + f64 re-rank
// block = 16 queries x 16 segment-threads; keys[16][256] u64; rank-count.
__global__ __launch_bounds__(256) void knnconv_s2(const float4* __restrict__ pos4,
                                                  const u16* __restrict__ g1,
                                                  const u16* __restrict__ gcnt,
                                                  u16* __restrict__ knn_out) {
  __shared__ u64 keys[16 * 256];         // 32KB
  __shared__ int Tq[16];
  const int tid = threadIdx.x;
  const int iq = tid >> 4, s = tid & 15;
  const int q0 = blockIdx.x * 16;
  const int q = q0 + iq;

  #pragma unroll
  for (int i = 0; i < 16; ++i) keys[i * 256 + tid] = ~0ULL;
  __syncthreads();

  int off = 0, T = 0;
  #pragma unroll
  for (int j = 0; j < NSEG; ++j) {
    int cj = gcnt[q * NSEG + j];
    off += (j < s) ? cj : 0;
    T += cj;
  }
  if (s == 15) Tq[iq] = min(T, 256);
  int myc = gcnt[q * NSEG + s];
  float4 P = pos4[q];
  for (int i = 0; i < myc; ++i) {
    int pos = off + i;
    if (pos >= 256) break;               // deterministic clamp (P ~ 0)
    int cidx = (int)g1[(q * NSEG + s) * SCAP + i];
    float4 C = pos4[cidx];
    double qx = P.x, qy = P.y, qz = P.z;
    double cx = C.x, cy = C.y, cz = C.z;
    double sqq = qx * qx + qy * qy + qz * qz;
    double sqc = cx * cx + cy * cy + cz * cz;
    double dot = qx * cx + qy * cy + qz * cz;
    double d   = (sqq + sqc) - 2.0 * dot;              // exact to ~1e-16
    float df = fmaxf((float)d, 0.0f);                  // one rounding, 6e-8 rel
    keys[iq * 256 + pos] = ((u64)__builtin_bit_cast(u32, df) << 14) | (u32)cidx;
  }
  __syncthreads();

  #pragma unroll 1
  for (int t = 0; t < 16; ++t) {         // uniform per-block iteration
    int T2 = Tq[t];
    if (tid < T2) {
      u64 kj = keys[t * 256 + tid];
      const u64* row = keys + t * 256;
      int r = 0;
      for (int k = 0; k < T2; ++k) r += (row[k] < kj) ? 1 : 0;   // broadcast reads
      if (r < KNNK)
        knn_out[(q0 + t) * KNNK + r] = (u16)(kj & 0x3FFFu);
    }
  }
}

// ---------------------------------------------------------------- W1/W2 -> pre-swizzled bf16 (one-shot)
__global__ __launch_bounds__(256) void knnconv_wprep(const float* __restrict__ W1,
                                                     const float* __restrict__ W2,
                                                     u16* __restrict__ w1bf,
                                                     u16* __restrict__ w2bf) {
  int b = blockIdx.x;
  if (b < 128) {
    int e = b * 256 + threadIdx.x;       // 32768 entries
    int n = e >> 7, kk = e & 127;
    float v;
    if (n < 128) v = W1[(128 + kk) * 128 + n];                              // W1d
    else { int n2 = n - 128; v = W1[kk * 128 + n2] - W1[(128 + kk) * 128 + n2]; }  // W1c-W1d
    w1bf[(n * 256 + ((kk * 2) ^ ((n & 7) << 4))) >> 1] = f2bf(v);
  } else {
    int e = (b - 128) * 256 + threadIdx.x;   // 16384 entries
    int n = e >> 7, kk = e & 127;
    w2bf[(n * 256 + ((kk * 2) ^ ((n & 7) << 4))) >> 1] = f2bf(W2[kk * 128 + n]);
  }
}

// ---------------------------------------------------------------- precompute a = f@W1d (bf16), c = f@(W1c-W1d)+b1 (f32)
__global__ __launch_bounds__(256) void knnconv_prec(const float* __restrict__ feat,
                                                    const u16* __restrict__ w1bf,
                                                    const float* __restrict__ b1,
                                                    u16* __restrict__ a_out,
                                                    float* __restrict__ c_out) {
  __shared__ char sW[65536];   // WT[n=256][k=128] bf16, pre-swizzled (linear copy)
  __shared__ char sF[16384];   // FA[m=64][k=128] bf16, XOR-swizzled
  const int tid = threadIdx.x;
  { // linear coalesced copy of pre-swizzled W1-combined
    const uint4* src = (const uint4*)w1bf;
    uint4* dst = (uint4*)sW;
    #pragma unroll
    for (int r = 0; r < 16; ++r) dst[r * 256 + tid] = src[r * 256 + tid];
  }
  { // stage FA rows (bf16x8 per lane)
    int sub = tid & 15, r0 = tid >> 4;
    int m0 = blockIdx.x * 64;
    for (int rr = 0; rr < 4; ++rr) {
      int r = r0 + rr * 16;
      const float* src = feat + (m0 + r) * 128 + sub * 8;
      float4 v0 = *(const float4*)src;
      float4 v1 = *(const float4*)(src + 4);
      u32 p0 = (u32)f2bf(v0.x) | ((u32)f2bf(v0.y) << 16);
      u32 p1 = (u32)f2bf(v0.z) | ((u32)f2bf(v0.w) << 16);
      u32 p2 = (u32)f2bf(v1.x) | ((u32)f2bf(v1.y) << 16);
      u32 p3 = (u32)f2bf(v1.z) | ((u32)f2bf(v1.w) << 16);
      *(uint4*)(sF + r * 256 + ((sub * 16) ^ ((r & 7) << 4))) = make_uint4(p0, p1, p2, p3);
    }
  }
  __syncthreads();
  const int lane = tid & 63, wv = tid >> 6;
  const int l15 = lane & 15, l4 = lane >> 4;
  f32x4 acc[4][4];
  #pragma unroll
  for (int a = 0; a < 4; ++a)
    #pragma unroll
    for (int b = 0; b < 4; ++b) acc[a][b] = (f32x4){0.f, 0.f, 0.f, 0.f};
  #pragma unroll
  for (int kk = 0; kk < 4; ++kk) {
    int kb = kk * 64 + l4 * 16;
    s16x8 af[4], bfr[4];
    #pragma unroll
    for (int mt = 0; mt < 4; ++mt) {
      int row = mt * 16 + l15;
      af[mt] = *(const s16x8*)(sF + row * 256 + (kb ^ ((row & 7) << 4)));
    }
    #pragma unroll
    for (int nt = 0; nt < 4; ++nt) {
      int n = (wv * 4 + nt) * 16 + l15;
      bfr[nt] = *(const s16x8*)(sW + n * 256 + (kb ^ ((n & 7) << 4)));
    }
    #pragma unroll
    for (int mt = 0; mt < 4; ++mt)
      #pragma unroll
      for (int nt = 0; nt < 4; ++nt)
        acc[mt][nt] = MFMA_BF16(af[mt], bfr[nt], acc[mt][nt], 0, 0, 0);
  }
  int m0 = blockIdx.x * 64;
  #pragma unroll
  for (int nt = 0; nt < 4; ++nt) {
    int n = (wv * 4 + nt) * 16 + l15;
    float bias = (n >= 128) ? b1[n - 128] : 0.0f;
    #pragma unroll
    for (int mt = 0; mt < 4; ++mt)
      #pragma unroll
      for (int r = 0; r < 4; ++r) {
        int m = m0 + mt * 16 + l4 * 4 + r;    // C/D: row=(l>>4)*4+reg, col=l&15
        float v = acc[mt][nt][r];
        if (n < 128) a_out[m * 128 + n] = f2bf(v);
        else         c_out[m * 128 + (n - 128)] = v + bias;
      }
  }
}

// ---------------------------------------------------------------- fused gather + relu + GEMM2 + max
__global__ __launch_bounds__(256) void knnconv_conv(const u16* __restrict__ knn,
                                                    const u16* __restrict__ a_in,
                                                    const float* __restrict__ c_in,
                                                    const u16* __restrict__ w2bf,
                                                    const float* __restrict__ b2,
                                                    float* __restrict__ out) {
  __shared__ char lds[77824];     // [0,40960): A / H2  | [40960,73728): W2T | [73728,77824): c rows
  char* sA = lds;
  char* sW = lds + 40960;
  char* sC = lds + 73728;
  const int tid = threadIdx.x;
  const int q0 = blockIdx.x * 8;

  { // stage c rows for the 8 queries
    int row = tid >> 5, ch4 = (tid & 31) * 4;
    *(float4*)(sC + (row * 128 + ch4) * 4) = *(const float4*)(c_in + (q0 + row) * 128 + ch4);
  }
  __syncthreads();
  { // copy pre-swizzled W2 bf16 (linear copy; layout already swizzled)
    const uint4* src = (const uint4*)w2bf;
    uint4* dst = (uint4*)sW;
    #pragma unroll
    for (int r = 0; r < 8; ++r) dst[r * 256 + tid] = src[r * 256 + tid];
  }
  { // stage A: row r = (query il, neighbor ke): relu(a[idx] + c[il]) -> bf16, swizzled
    int sub = tid & 15, rr = tid >> 4;
    for (int p = 0; p < 10; ++p) {
      int r = p * 16 + rr;
      int il = r / 20;
      int ke = r - il * 20;
      int idx = (int)knn[(q0 + il) * KNNK + ke];
      uint4 av = *(const uint4*)(a_in + idx * 128 + sub * 8);
      float4 c0 = *(const float4*)(sC + (il * 128 + sub * 8) * 4);
      float4 c1 = *(const float4*)(sC + (il * 128 + sub * 8 + 4) * 4);
      float h0 = fmaxf(bf2f((u16)(av.x & 0xFFFF)) + c0.x, 0.f);
      float h1 = fmaxf(bf2f((u16)(av.x >> 16))    + c0.y, 0.f);
      float h2 = fmaxf(bf2f((u16)(av.y & 0xFFFF)) + c0.z, 0.f);
      float h3 = fmaxf(bf2f((u16)(av.y >> 16))    + c0.w, 0.f);
      float h4 = fmaxf(bf2f((u16)(av.z & 0xFFFF)) + c1.x, 0.f);
      float h5 = fmaxf(bf2f((u16)(av.z >> 16))    + c1.y, 0.f);
      float h6 = fmaxf(bf2f((u16)(av.w & 0xFFFF)) + c1.z, 0.f);
      float h7 = fmaxf(bf2f((u16)(av.w >> 16))    + c1.w, 0.f);
      u32 p0 = (u32)f2bf(h0) | ((u32)f2bf(h1) << 16);
      u32 p1 = (u32)f2bf(h2) | ((u32)f2bf(h3) << 16);
      u32 p2 = (u32)f2bf(h4) | ((u32)f2bf(h5) << 16);
      u32 p3 = (u32)f2bf(h6) | ((u32)f2bf(h7) << 16);
      *(uint4*)(sA + r * 256 + ((sub * 16) ^ ((r & 7) << 4))) = make_uint4(p0, p1, p2, p3);
    }
  }
  __syncthreads();
  const int lane = tid & 63, wv = tid >> 6;
  const int l15 = lane & 15, l4 = lane >> 4;
  f32x4 acc[10][2];
  #pragma unroll
  for (int mt = 0; mt < 10; ++mt) { acc[mt][0] = (f32x4){0,0,0,0}; acc[mt][1] = (f32x4){0,0,0,0}; }
  #pragma unroll
  for (int kk = 0; kk < 4; ++kk) {
    int kb = kk * 64 + l4 * 16;
    s16x8 b0, b1r;
    { int n = (wv * 2 + 0) * 16 + l15; b0  = *(const s16x8*)(sW + n * 256 + (kb ^ ((n & 7) << 4))); }
    { int n = (wv * 2 + 1) * 16 + l15; b1r = *(const s16x8*)(sW + n * 256 + (kb ^ ((n & 7) << 4))); }
    #pragma unroll
    for (int mt = 0; mt < 10; ++mt) {
      int row = mt * 16 + l15;
      s16x8 a = *(const s16x8*)(sA + row * 256 + (kb ^ ((row & 7) << 4)));
      acc[mt][0] = MFMA_BF16(a, b0,  acc[mt][0], 0, 0, 0);
      acc[mt][1] = MFMA_BF16(a, b1r, acc[mt][1], 0, 0, 0);
    }
  }
  __syncthreads();              // all waves done reading A before H2 overwrite
  #pragma unroll
  for (int mt = 0; mt < 10; ++mt)
    #pragma unroll
    for (int nt = 0; nt < 2; ++nt) {
      int n = (wv * 2 + nt) * 16 + l15;
      #pragma unroll
      for (int r = 0; r < 4; ++r) {
        int row = mt * 16 + l4 * 4 + r;
        *(u16*)(sA + row * 256 + n * 2) = f2bf(acc[mt][nt][r]);  // H2, plain layout
      }
    }
  __syncthreads();
  { // max over 20 neighbors + b2
    int ch = tid & 127, g = tid >> 7;
    float bias = b2[ch];
    for (int pp = 0; pp < 4; ++pp) {
      int qq = pp * 2 + g;
      float mx = -__builtin_inff();
      #pragma unroll
      for (int e = 0; e < KNNK; ++e)
        mx = fmaxf(mx, bf2f(*(const u16*)(sA + (qq * 20 + e) * 256 + ch * 2)));
      out[(q0 + qq) * 128 + ch] = mx + bias;
    }
  }
}

// ---------------------------------------------------------------- launch
extern "C" void kernel_launch(void* const* d_in, const int* in_sizes, int n_in,
                              void* d_out, int out_size, void* d_ws, size_t ws_size,
                              hipStream_t stream) {
  const float* pos  = (const float*)d_in[0];
  const float* feat = (const float*)d_in[1];
  const float* W1   = (const float*)d_in[2];
  const float* b1   = (const float*)d_in[3];
  const float* W2   = (const float*)d_in[4];
  const float* b2   = (const float*)d_in[5];
  float* out = (float*)d_out;
  char* ws = (char*)d_ws;
  // ws layout (aliases noted):
  //  [0,256K)              pos4 (prep..s2)        -> w1bf 64KB + w2bf 32KB (wprep..conv)
  //  [256K,917504)         knn u16 (s2..conv)
  //  [917504,13500416)     g1 [16384][16][24] u16 (s1x..s2) -> a_buf 4MB + c_buf 8MB (prec..conv)
  //  [13500416,14024704)   gcnt [16384][16] u16 (s1x..s2)
  //  [14024704,14090240)   tau [16384] f32 (s0..s1x)
  float4* pos4  = (float4*)ws;
  u16*    w1bf  = (u16*)ws;
  u16*    w2bf  = (u16*)(ws + 65536);
  u16*    knn   = (u16*)(ws + 262144);
  u16*    g1    = (u16*)(ws + 917504);
  u16*    a_buf = (u16*)(ws + 917504);
  float*  c_buf = (float*)(ws + 5111808);
  u16*    gcnt  = (u16*)(ws + 13500416);
  float*  tau   = (float*)(ws + 14024704);
  if (ws_size < 14090240) return;   // insufficient scratch (would corrupt)

  knnconv_prep<<<64, 256, 0, stream>>>(pos, pos4);
  knnconv_s0<<<256, 512, 0, stream>>>(pos4, tau);
  knnconv_s1x<<<1024, 256, 0, stream>>>(pos4, tau, g1, gcnt);
  knnconv_s2<<<1024, 256, 0, stream>>>(pos4, g1, gcnt, knn);
  knnconv_wprep<<<192, 256, 0, stream>>>(W1, W2, w1bf, w2bf);          // overwrites pos4 (dead)
  knnconv_prec<<<256, 256, 0, stream>>>(feat, w1bf, b1, a_buf, c_buf); // overwrites g1 (dead)
  knnconv_conv<<<2048, 256, 0, stream>>>(knn, a_buf, c_buf, w2bf, b2, out);
}

// Round 12
// 262.970 us; speedup vs baseline: 1.2863x; 1.0323x over previous
//
#include <hip/hip_runtime.h>

typedef unsigned short u16;
typedef unsigned int   u32;
typedef unsigned long long u64;
typedef short s16x8 __attribute__((ext_vector_type(8)));   // 8 x bf16 bits (4 VGPRs)
typedef float f32x4 __attribute__((ext_vector_type(4)));   // MFMA accumulator

#define NPTS   16384
#define KNNK   20
#define SLOTS0 24      // s0 stack slots (trigger 16, growth <= 8 => max 23)
#define TRIG0  16
#define NSEG   16      // s1x candidate parts per query
#define PSZ    1024    // candidates per part
#define SCAP   24      // survivor cap per (query, part)  [E~5; P(overflow) ~1e-4 total]

#define MFMA_BF16 __builtin_amdgcn_mfma_f32_16x16x32_bf16

__device__ __forceinline__ u16 f2bf(float x) {
  u32 u = __builtin_bit_cast(u32, x);
  u32 r = (u + 0x7FFFu + ((u >> 16) & 1u)) >> 16;   // RNE
  return (u16)r;
}
__device__ __forceinline__ float bf2f(u16 b) {
  u32 u = ((u32)b) << 16;
  return __builtin_bit_cast(float, u);
}
__device__ __forceinline__ float dist2(float4 qp, float4 cd) {
  float dot = fmaf(qp.x, cd.x, fmaf(qp.y, cd.y, qp.z * cd.z));
  return fmaf(-2.0f, dot, qp.w + cd.w);
}

// ---------------------------------------------------------------- prep: pos4 = (x,y,z,|p|^2)
__global__ __launch_bounds__(256) void knnconv_prep(const float* __restrict__ pos,
                                                    float4* __restrict__ pos4) {
  int i = blockIdx.x * 256 + threadIdx.x;
  float x = pos[i * 3 + 0], y = pos[i * 3 + 1], z = pos[i * 3 + 2];
  float sq = (x * x + y * y) + z * z;    // f32 screen only; f64 re-rank decides final set
  pos4[i] = make_float4(x, y, z, sq);
}

// ---------------------------------------------------------------- s0: sample threshold
// grid 256 (query-group); block 1024 = 16 waves -> 4 waves/SIMD at 1 block/CU.
// lane = query; wave wv scans 256 samples (every 4th point, same 4096-sample set
// as before -> identical tau). Lazy stack + pair-carry flush; 16-way merge of
// sorted top-20 lists -> exact sample-20th -> tau (x1.00001 safety).
__global__ __launch_bounds__(1024) void knnconv_s0(const float4* __restrict__ pos4,
                                                   float* __restrict__ tau) {
  __shared__ float lds0[SLOTS0 * 1024];  // 96KB stacks; aliased as md[16][64][20] (80KB)
  float* sd = lds0;
  float* md = lds0;
  const int tid  = threadIdx.x;
  const int lane = tid & 63;
  const int wv   = __builtin_amdgcn_readfirstlane(tid >> 6);   // 0..15, uniform
  const int qg   = blockIdx.x;
  const int q    = qg * 64 + lane;
  const float4 qp = pos4[q];
  const float INF = __builtin_inff();

  float top[KNNK];
  #pragma unroll
  for (int j = 0; j < KNNK; ++j) top[j] = INF;
  float thrF = INF;
  int cnt = 0;
  const int kbase = wv * 256;            // sample index base (sample i -> point 4i)

#define FLUSH0()                                                      \
  { _Pragma("unroll 1")                                               \
    for (int e = 0; e < SLOTS0; e += 2) {                             \
      if (!__any(e < cnt)) break;                                     \
      float lo = (e     < cnt) ? sd[e * 1024 + tid]       : INF;      \
      float hi = (e + 1 < cnt) ? sd[(e + 1) * 1024 + tid] : INF;      \
      float a_ = fminf(lo, hi), b_ = fmaxf(lo, hi);                   \
      lo = a_; hi = b_;                                               \
      _Pragma("unroll")                                               \
      for (int j = 0; j < KNNK; ++j) {                                \
        float t = top[j];                                             \
        float m = fminf(lo, t);                                       \
        float x = fmaxf(lo, t);                                       \
        top[j] = m;                                                   \
        lo = fminf(x, hi);                                            \
        hi = fmaxf(x, hi);                                            \
      }                                                               \
    }                                                                 \
    thrF = top[KNNK - 1];                                             \
    cnt = 0; }

  for (int t0 = 0; t0 < 256; t0 += 8) {
    float4 g[8];
    #pragma unroll
    for (int u = 0; u < 8; ++u) g[u] = pos4[(kbase + t0 + u) * 4];  // wave-uniform loads
    #pragma unroll
    for (int u = 0; u < 8; ++u) {
      float d2 = dist2(qp, g[u]);
      sd[cnt * 1024 + tid] = d2;                       // unconditional (slot <= 22 valid)
      cnt += (d2 < thrF) ? 1 : 0;                      // branchless accept
    }
    if (__any(cnt >= TRIG0)) { FLUSH0(); }
  }
  FLUSH0();

  __syncthreads();                       // stacks dead before md alias
  #pragma unroll
  for (int j = 0; j < KNNK; ++j) md[(wv * 64 + lane) * KNNK + j] = top[j];
  __syncthreads();

  if (tid < 64) {                        // 16-way merge, take 20th smallest (value only)
    int ql = tid;
    int h0=0,h1=0,h2=0,h3=0,h4=0,h5=0,h6=0,h7=0;
    int h8=0,h9=0,h10=0,h11=0,h12=0,h13=0,h14=0,h15=0;
    float last = INF;
    for (int r = 0; r < KNNK; ++r) {     // heads <= r <= 19 at read time
      float c0 = md[( 0*64+ql)*KNNK+h0],  c1 = md[( 1*64+ql)*KNNK+h1];
      float c2 = md[( 2*64+ql)*KNNK+h2],  c3 = md[( 3*64+ql)*KNNK+h3];
      float c4 = md[( 4*64+ql)*KNNK+h4],  c5 = md[( 5*64+ql)*KNNK+h5];
      float c6 = md[( 6*64+ql)*KNNK+h6],  c7 = md[( 7*64+ql)*KNNK+h7];
      float c8 = md[( 8*64+ql)*KNNK+h8],  c9 = md[( 9*64+ql)*KNNK+h9];
      float cA = md[(10*64+ql)*KNNK+h10], cB = md[(11*64+ql)*KNNK+h11];
      float cC = md[(12*64+ql)*KNNK+h12], cD = md[(13*64+ql)*KNNK+h13];
      float cE = md[(14*64+ql)*KNNK+h14], cF = md[(15*64+ql)*KNNK+h15];
      float bv = c0; int bw = 0;
      if (c1 < bv) { bv = c1; bw = 1; }
      if (c2 < bv) { bv = c2; bw = 2; }
      if (c3 < bv) { bv = c3; bw = 3; }
      if (c4 < bv) { bv = c4; bw = 4; }
      if (c5 < bv) { bv = c5; bw = 5; }
      if (c6 < bv) { bv = c6; bw = 6; }
      if (c7 < bv) { bv = c7; bw = 7; }
      if (c8 < bv) { bv = c8; bw = 8; }
      if (c9 < bv) { bv = c9; bw = 9; }
      if (cA < bv) { bv = cA; bw = 10; }
      if (cB < bv) { bv = cB; bw = 11; }
      if (cC < bv) { bv = cC; bw = 12; }
      if (cD < bv) { bv = cD; bw = 13; }
      if (cE < bv) { bv = cE; bw = 14; }
      if (cF < bv) { bv = cF; bw = 15; }
      last = bv;
      h0  += (bw==0);  h1  += (bw==1);  h2  += (bw==2);  h3  += (bw==3);
      h4  += (bw==4);  h5  += (bw==5);  h6  += (bw==6);  h7  += (bw==7);
      h8  += (bw==8);  h9  += (bw==9);  h10 += (bw==10); h11 += (bw==11);
      h12 += (bw==12); h13 += (bw==13); h14 += (bw==14); h15 += (bw==15);
    }
    tau[qg * 64 + ql] = last * 1.00001f;
  }
}

// ---------------------------------------------------------------- s1x: scalar-broadcast screen
// grid 1024 = 256 qg x 4 part-blocks; block 4 waves; wave -> part = pb*4+wv.
// LANE = QUERY (Q + tau'' + survivor COUNTER all in registers); candidates via
// wave-uniform scalar loads. Accept: fmaf(0.5,cw,-dot) <= Qt.
// Survivors -> private per-(q,part) global segment: no atomics, no LDS.
__global__ __launch_bounds__(256) void knnconv_s1x(const float4* __restrict__ pos4,
                                                   const float* __restrict__ tau,
                                                   u16* __restrict__ g1,
                                                   u16* __restrict__ gcnt) {
  const int tid  = threadIdx.x;
  const int lane = tid & 63;
  const int wv   = __builtin_amdgcn_readfirstlane(tid >> 6);   // uniform -> SGPR
  const int qg   = blockIdx.x >> 2;
  const int pb   = blockIdx.x & 3;
  const int part = pb * 4 + wv;          // 0..15, one wave owns one part
  const int q    = qg * 64 + lane;
  const float4 P = pos4[q];
  const float Qx = P.x, Qy = P.y, Qz = P.z;
  const float Qt = 0.5f * (tau[q] - P.w);
  const int cbase = part * PSZ;
  const float4* cp = pos4 + cbase;       // SGPR base -> s_load candidates
  u16* seg = g1 + (q * NSEG + part) * SCAP;
  int cnt = 0;

  #pragma unroll 1
  for (int t0 = 0; t0 < PSZ; t0 += 8) {
    float4 c[8];
    #pragma unroll
    for (int u = 0; u < 8; ++u) c[u] = cp[t0 + u];     // wave-uniform scalar loads
    #pragma unroll
    for (int u = 0; u < 8; ++u) {
      float dot = fmaf(Qx, c[u].x, fmaf(Qy, c[u].y, Qz * c[u].z));
      float lhs = fmaf(0.5f, c[u].w, -dot);            // 0.5*cw - dot
      if (lhs <= Qt) {                                 // rare (p ~ 0.5% per lane)
        if (cnt < SCAP) seg[cnt] = (u16)(cbase + t0 + u);
        ++cnt;
      }
    }
  }
  gcnt[q * NSEG + part] = (u16)min(cnt, SCAP);
}

// ---------------------------------------------------------------- s2: gather + f64 re-rank
// block = 16 queries x 16 segment-threads; keys[16][256] u64; rank-count.
__global__ __launch_bounds__(256) void knnconv_s2(const float4* __restrict__ pos4,
                                                  const u16* __restrict__ g1,
                                                  const u16* __restrict__ gcnt,
                                                  u16* __restrict__ knn_out) {
  __shared__ u64 keys[16 * 256];         // 32KB
  __shared__ int Tq[16];
  const int tid = threadIdx.x;
  const int iq = tid >> 4, s = tid & 15;
  const int q0 = blockIdx.x * 16;
  const int q = q0 + iq;

  #pragma unroll
  for (int i = 0; i < 16; ++i) keys[i * 256 + tid] = ~0ULL;
  __syncthreads();

  int off = 0, T = 0;
  #pragma unroll
  for (int j = 0; j < NSEG; ++j) {
    int cj = gcnt[q * NSEG + j];
    off += (j < s) ? cj : 0;
    T += cj;
  }
  if (s == 15) Tq[iq] = min(T, 256);
  int myc = gcnt[q * NSEG + s];
  float4 P = pos4[q];
  for (int i = 0; i < myc; ++i) {
    int pos = off + i;
    if (pos >= 256) break;               // deterministic clamp (P ~ 0)
    int cidx = (int)g1[(q * NSEG + s) * SCAP + i];
    float4 C = pos4[cidx];
    double qx = P.x, qy = P.y, qz = P.z;
    double cx = C.x, cy = C.y, cz = C.z;
    double sqq = qx * qx + qy * qy + qz * qz;
    double sqc = cx * cx + cy * cy + cz * cz;
    double dot = qx * cx + qy * cy + qz * cz;
    double d   = (sqq + sqc) - 2.0 * dot;              // exact to ~1e-16
    float df = fmaxf((float)d, 0.0f);                  // one rounding, 6e-8 rel
    keys[iq * 256 + pos] = ((u64)__builtin_bit_cast(u32, df) << 14) | (u32)cidx;
  }
  __syncthreads();

  #pragma unroll 1
  for (int t = 0; t < 16; ++t) {         // uniform per-block iteration
    int T2 = Tq[t];
    if (tid < T2) {
      u64 kj = keys[t * 256 + tid];
      const u64* row = keys + t * 256;
      int r = 0;
      for (int k = 0; k < T2; ++k) r += (row[k] < kj) ? 1 : 0;   // broadcast reads
      if (r < KNNK)
        knn_out[(q0 + t) * KNNK + r] = (u16)(kj & 0x3FFFu);
    }
  }
}

// ---------------------------------------------------------------- W1/W2 -> pre-swizzled bf16 (one-shot)
__global__ __launch_bounds__(256) void knnconv_wprep(const float* __restrict__ W1,
                                                     const float* __restrict__ W2,
                                                     u16* __restrict__ w1bf,
                                                     u16* __restrict__ w2bf) {
  int b = blockIdx.x;
  if (b < 128) {
    int e = b * 256 + threadIdx.x;       // 32768 entries
    int n = e >> 7, kk = e & 127;
    float v;
    if (n < 128) v = W1[(128 + kk) * 128 + n];                              // W1d
    else { int n2 = n - 128; v = W1[kk * 128 + n2] - W1[(128 + kk) * 128 + n2]; }  // W1c-W1d
    w1bf[(n * 256 + ((kk * 2) ^ ((n & 7) << 4))) >> 1] = f2bf(v);
  } else {
    int e = (b - 128) * 256 + threadIdx.x;   // 16384 entries
    int n = e >> 7, kk = e & 127;
    w2bf[(n * 256 + ((kk * 2) ^ ((n & 7) << 4))) >> 1] = f2bf(W2[kk * 128 + n]);
  }
}

// ---------------------------------------------------------------- precompute a = f@W1d (bf16), c = f@(W1c-W1d)+b1 (f32)
__global__ __launch_bounds__(256) void knnconv_prec(const float* __restrict__ feat,
                                                    const u16* __restrict__ w1bf,
                                                    const float* __restrict__ b1,
                                                    u16* __restrict__ a_out,
                                                    float* __restrict__ c_out) {
  __shared__ char sW[65536];   // WT[n=256][k=128] bf16, pre-swizzled (linear copy)
  __shared__ char sF[16384];   // FA[m=64][k=128] bf16, XOR-swizzled
  const int tid = threadIdx.x;
  { // linear coalesced copy of pre-swizzled W1-combined
    const uint4* src = (const uint4*)w1bf;
    uint4* dst = (uint4*)sW;
    #pragma unroll
    for (int r = 0; r < 16; ++r) dst[r * 256 + tid] = src[r * 256 + tid];
  }
  { // stage FA rows (bf16x8 per lane)
    int sub = tid & 15, r0 = tid >> 4;
    int m0 = blockIdx.x * 64;
    for (int rr = 0; rr < 4; ++rr) {
      int r = r0 + rr * 16;
      const float* src = feat + (m0 + r) * 128 + sub * 8;
      float4 v0 = *(const float4*)src;
      float4 v1 = *(const float4*)(src + 4);
      u32 p0 = (u32)f2bf(v0.x) | ((u32)f2bf(v0.y) << 16);
      u32 p1 = (u32)f2bf(v0.z) | ((u32)f2bf(v0.w) << 16);
      u32 p2 = (u32)f2bf(v1.x) | ((u32)f2bf(v1.y) << 16);
      u32 p3 = (u32)f2bf(v1.z) | ((u32)f2bf(v1.w) << 16);
      *(uint4*)(sF + r * 256 + ((sub * 16) ^ ((r & 7) << 4))) = make_uint4(p0, p1, p2, p3);
    }
  }
  __syncthreads();
  const int lane = tid & 63, wv = tid >> 6;
  const int l15 = lane & 15, l4 = lane >> 4;
  f32x4 acc[4][4];
  #pragma unroll
  for (int a = 0; a < 4; ++a)
    #pragma unroll
    for (int b = 0; b < 4; ++b) acc[a][b] = (f32x4){0.f, 0.f, 0.f, 0.f};
  #pragma unroll
  for (int kk = 0; kk < 4; ++kk) {
    int kb = kk * 64 + l4 * 16;
    s16x8 af[4], bfr[4];
    #pragma unroll
    for (int mt = 0; mt < 4; ++mt) {
      int row = mt * 16 + l15;
      af[mt] = *(const s16x8*)(sF + row * 256 + (kb ^ ((row & 7) << 4)));
    }
    #pragma unroll
    for (int nt = 0; nt < 4; ++nt) {
      int n = (wv * 4 + nt) * 16 + l15;
      bfr[nt] = *(const s16x8*)(sW + n * 256 + (kb ^ ((n & 7) << 4)));
    }
    #pragma unroll
    for (int mt = 0; mt < 4; ++mt)
      #pragma unroll
      for (int nt = 0; nt < 4; ++nt)
        acc[mt][nt] = MFMA_BF16(af[mt], bfr[nt], acc[mt][nt], 0, 0, 0);
  }
  int m0 = blockIdx.x * 64;
  #pragma unroll
  for (int nt = 0; nt < 4; ++nt) {
    int n = (wv * 4 + nt) * 16 + l15;
    float bias = (n >= 128) ? b1[n - 128] : 0.0f;
    #pragma unroll
    for (int mt = 0; mt < 4; ++mt)
      #pragma unroll
      for (int r = 0; r < 4; ++r) {
        int m = m0 + mt * 16 + l4 * 4 + r;    // C/D: row=(l>>4)*4+reg, col=l&15
        float v = acc[mt][nt][r];
        if (n < 128) a_out[m * 128 + n] = f2bf(v);
        else         c_out[m * 128 + (n - 128)] = v + bias;
      }
  }
}

// ---------------------------------------------------------------- fused gather + relu + GEMM2 + max
__global__ __launch_bounds__(256) void knnconv_conv(const u16* __restrict__ knn,
                                                    const u16* __restrict__ a_in,
                                                    const float* __restrict__ c_in,
                                                    const u16* __restrict__ w2bf,
                                                    const float* __restrict__ b2,
                                                    float* __restrict__ out) {
  __shared__ char lds[77824];     // [0,40960): A / H2  | [40960,73728): W2T | [73728,77824): c rows
  char* sA = lds;
  char* sW = lds + 40960;
  char* sC = lds + 73728;
  const int tid = threadIdx.x;
  const int q0 = blockIdx.x * 8;

  { // stage c rows for the 8 queries
    int row = tid >> 5, ch4 = (tid & 31) * 4;
    *(float4*)(sC + (row * 128 + ch4) * 4) = *(const float4*)(c_in + (q0 + row) * 128 + ch4);
  }
  __syncthreads();
  { // copy pre-swizzled W2 bf16 (linear copy; layout already swizzled)
    const uint4* src = (const uint4*)w2bf;
    uint4* dst = (uint4*)sW;
    #pragma unroll
    for (int r = 0; r < 8; ++r) dst[r * 256 + tid] = src[r * 256 + tid];
  }
  { // stage A: row r = (query il, neighbor ke): relu(a[idx] + c[il]) -> bf16, swizzled
    int sub = tid & 15, rr = tid >> 4;
    for (int p = 0; p < 10; ++p) {
      int r = p * 16 + rr;
      int il = r / 20;
      int ke = r - il * 20;
      int idx = (int)knn[(q0 + il) * KNNK + ke];
      uint4 av = *(const uint4*)(a_in + idx * 128 + sub * 8);
      float4 c0 = *(const float4*)(sC + (il * 128 + sub * 8) * 4);
      float4 c1 = *(const float4*)(sC + (il * 128 + sub * 8 + 4) * 4);
      float h0 = fmaxf(bf2f((u16)(av.x & 0xFFFF)) + c0.x, 0.f);
      float h1 = fmaxf(bf2f((u16)(av.x >> 16))    + c0.y, 0.f);
      float h2 = fmaxf(bf2f((u16)(av.y & 0xFFFF)) + c0.z, 0.f);
      float h3 = fmaxf(bf2f((u16)(av.y >> 16))    + c0.w, 0.f);
      float h4 = fmaxf(bf2f((u16)(av.z & 0xFFFF)) + c1.x, 0.f);
      float h5 = fmaxf(bf2f((u16)(av.z >> 16))    + c1.y, 0.f);
      float h6 = fmaxf(bf2f((u16)(av.w & 0xFFFF)) + c1.z, 0.f);
      float h7 = fmaxf(bf2f((u16)(av.w >> 16))    + c1.w, 0.f);
      u32 p0 = (u32)f2bf(h0) | ((u32)f2bf(h1) << 16);
      u32 p1 = (u32)f2bf(h2) | ((u32)f2bf(h3) << 16);
      u32 p2 = (u32)f2bf(h4) | ((u32)f2bf(h5) << 16);
      u32 p3 = (u32)f2bf(h6) | ((u32)f2bf(h7) << 16);
      *(uint4*)(sA + r * 256 + ((sub * 16) ^ ((r & 7) << 4))) = make_uint4(p0, p1, p2, p3);
    }
  }
  __syncthreads();
  const int lane = tid & 63, wv = tid >> 6;
  const int l15 = lane & 15, l4 = lane >> 4;
  f32x4 acc[10][2];
  #pragma unroll
  for (int mt = 0; mt < 10; ++mt) { acc[mt][0] = (f32x4){0,0,0,0}; acc[mt][1] = (f32x4){0,0,0,0}; }
  #pragma unroll
  for (int kk = 0; kk < 4; ++kk) {
    int kb = kk * 64 + l4 * 16;
    s16x8 b0, b1r;
    { int n = (wv * 2 + 0) * 16 + l15; b0  = *(const s16x8*)(sW + n * 256 + (kb ^ ((n & 7) << 4))); }
    { int n = (wv * 2 + 1) * 16 + l15; b1r = *(const s16x8*)(sW + n * 256 + (kb ^ ((n & 7) << 4))); }
    #pragma unroll
    for (int mt = 0; mt < 10; ++mt) {
      int row = mt * 16 + l15;
      s16x8 a = *(const s16x8*)(sA + row * 256 + (kb ^ ((row & 7) << 4)));
      acc[mt][0] = MFMA_BF16(a, b0,  acc[mt][0], 0, 0, 0);
      acc[mt][1] = MFMA_BF16(a, b1r, acc[mt][1], 0, 0, 0);
    }
  }
  __syncthreads();              // all waves done reading A before H2 overwrite
  #pragma unroll
  for (int mt = 0; mt < 10; ++mt)
    #pragma unroll
    for (int nt = 0; nt < 2; ++nt) {
      int n = (wv * 2 + nt) * 16 + l15;
      #pragma unroll
      for (int r = 0; r < 4; ++r) {
        int row = mt * 16 + l4 * 4 + r;
        *(u16*)(sA + row * 256 + n * 2) = f2bf(acc[mt][nt][r]);  // H2, plain layout
      }
    }
  __syncthreads();
  { // max over 20 neighbors + b2
    int ch = tid & 127, g = tid >> 7;
    float bias = b2[ch];
    for (int pp = 0; pp < 4; ++pp) {
      int qq = pp * 2 + g;
      float mx = -__builtin_inff();
      #pragma unroll
      for (int e = 0; e < KNNK; ++e)
        mx = fmaxf(mx, bf2f(*(const u16*)(sA + (qq * 20 + e) * 256 + ch * 2)));
      out[(q0 + qq) * 128 + ch] = mx + bias;
    }
  }
}

// ---------------------------------------------------------------- launch
extern "C" void kernel_launch(void* const* d_in, const int* in_sizes, int n_in,
                              void* d_out, int out_size, void* d_ws, size_t ws_size,
                              hipStream_t stream) {
  const float* pos  = (const float*)d_in[0];
  const float* feat = (const float*)d_in[1];
  const float* W1   = (const float*)d_in[2];
  const float* b1   = (const float*)d_in[3];
  const float* W2   = (const float*)d_in[4];
  const float* b2   = (const float*)d_in[5];
  float* out = (float*)d_out;
  char* ws = (char*)d_ws;
  // ws layout (aliases noted):
  //  [0,256K)              pos4 (prep..s2)        -> w1bf 64KB + w2bf 32KB (wprep..conv)
  //  [256K,917504)         knn u16 (s2..conv)
  //  [917504,13500416)     g1 [16384][16][24] u16 (s1x..s2) -> a_buf 4MB + c_buf 8MB (prec..conv)
  //  [13500416,14024704)   gcnt [16384][16] u16 (s1x..s2)
  //  [14024704,14090240)   tau [16384] f32 (s0..s1x)
  float4* pos4  = (float4*)ws;
  u16*    w1bf  = (u16*)ws;
  u16*    w2bf  = (u16*)(ws + 65536);
  u16*    knn   = (u16*)(ws + 262144);
  u16*    g1    = (u16*)(ws + 917504);
  u16*    a_buf = (u16*)(ws + 917504);
  float*  c_buf = (float*)(ws + 5111808);
  u16*    gcnt  = (u16*)(ws + 13500416);
  float*  tau   = (float*)(ws + 14024704);
  if (ws_size < 14090240) return;   // insufficient scratch (would corrupt)

  knnconv_prep<<<64, 256, 0, stream>>>(pos, pos4);
  knnconv_s0<<<256, 1024, 0, stream>>>(pos4, tau);
  knnconv_s1x<<<1024, 256, 0, stream>>>(pos4, tau, g1, gcnt);
  knnconv_s2<<<1024, 256, 0, stream>>>(pos4, g1, gcnt, knn);
  knnconv_wprep<<<192, 256, 0, stream>>>(W1, W2, w1bf, w2bf);          // overwrites pos4 (dead)
  knnconv_prec<<<256, 256, 0, stream>>>(feat, w1bf, b1, a_buf, c_buf); // overwrites g1 (dead)
  knnconv_conv<<<2048, 256, 0, stream>>>(knn, a_buf, c_buf, w2bf, b2, out);
}

// Round 13
// 226.553 us; speedup vs baseline: 1.4931x; 1.1607x over previous
//
#include <hip/hip_runtime.h>

typedef unsigned short u16;
typedef unsigned int   u32;
typedef unsigned long long u64;
typedef short s16x8 __attribute__((ext_vector_type(8)));   // 8 x bf16 bits (4 VGPRs)
typedef float f32x4 __attribute__((ext_vector_type(4)));   // MFMA accumulator

#define NPTS   16384
#define KNNK   20
#define SLOTS3 12      // s0 stack slots (trigger 4, growth <= 8 => max 11)
#define TRIG3  4
#define NSEG   16      // s1x candidate parts per query
#define PSZ    1024    // candidates per part
#define SCAP   24      // survivor cap per (query, part)  [E~5; P(overflow) ~1e-4 total]

#define MFMA_BF16 __builtin_amdgcn_mfma_f32_16x16x32_bf16

__device__ __forceinline__ u16 f2bf(float x) {
  u32 u = __builtin_bit_cast(u32, x);
  u32 r = (u + 0x7FFFu + ((u >> 16) & 1u)) >> 16;   // RNE
  return (u16)r;
}
__device__ __forceinline__ float bf2f(u16 b) {
  u32 u = ((u32)b) << 16;
  return __builtin_bit_cast(float, u);
}
__device__ __forceinline__ float dist2(float4 qp, float4 cd) {
  float dot = fmaf(qp.x, cd.x, fmaf(qp.y, cd.y, qp.z * cd.z));
  return fmaf(-2.0f, dot, qp.w + cd.w);
}

// ---------------------------------------------------------------- prep: pos4 = (x,y,z,|p|^2)
__global__ __launch_bounds__(256) void knnconv_prep(const float* __restrict__ pos,
                                                    float4* __restrict__ pos4) {
  int i = blockIdx.x * 256 + threadIdx.x;
  float x = pos[i * 3 + 0], y = pos[i * 3 + 1], z = pos[i * 3 + 2];
  float sq = (x * x + y * y) + z * z;    // f32 screen only; f64 re-rank decides final set
  pos4[i] = make_float4(x, y, z, sq);
}

// ---------------------------------------------------------------- s0: sample threshold
// grid 256 (query-group); block 1024 = 16 waves. lane = query; wave wv scans 256
// samples (every 4th point). Each wave keeps only TOP-3 (lazy stack, 3-stage
// pair-carry ladder). tau = 20th smallest of the 48-value union: its 20 smallest
// elements are sample points <= it, samples are a subset of the full set, so
// >=20 full points lie within tau -> provable superset bound (rank ~21 vs 20,
// survivors ~84 vs 80 -- negligible looseness, same downstream output).
__global__ __launch_bounds__(1024) void knnconv_s0(const float4* __restrict__ pos4,
                                                   float* __restrict__ tau) {
  __shared__ float sd[SLOTS3 * 1024];    // 48KB per-lane stacks
  __shared__ float md[16][64][4];        // 16KB sorted top-3 + INF sentinel
  const int tid  = threadIdx.x;
  const int lane = tid & 63;
  const int wv   = __builtin_amdgcn_readfirstlane(tid >> 6);   // 0..15, uniform
  const int qg   = blockIdx.x;
  const int q    = qg * 64 + lane;
  const float4 qp = pos4[q];
  const float INF = __builtin_inff();

  float t0v = INF, t1v = INF, t2v = INF; // sorted top-3 in registers
  float thrF = INF;
  int cnt = 0;
  const int kbase = wv * 256;            // sample index base (sample i -> point 4i)

#define FLUSH3()                                                      \
  { _Pragma("unroll 1")                                               \
    for (int e = 0; e < SLOTS3; e += 2) {                             \
      if (!__any(e < cnt)) break;                                     \
      float lo = (e     < cnt) ? sd[e * 1024 + tid]       : INF;      \
      float hi = (e + 1 < cnt) ? sd[(e + 1) * 1024 + tid] : INF;      \
      float a_ = fminf(lo, hi), b_ = fmaxf(lo, hi);                   \
      lo = a_; hi = b_;                                               \
      { float m = fminf(lo, t0v), x = fmaxf(lo, t0v);                 \
        t0v = m; lo = fminf(x, hi); hi = fmaxf(x, hi); }              \
      { float m = fminf(lo, t1v), x = fmaxf(lo, t1v);                 \
        t1v = m; lo = fminf(x, hi); hi = fmaxf(x, hi); }              \
      t2v = fminf(lo, t2v);                                           \
    }                                                                 \
    thrF = t2v;                                                       \
    cnt = 0; }

  for (int t0 = 0; t0 < 256; t0 += 8) {
    float4 g[8];
    #pragma unroll
    for (int u = 0; u < 8; ++u) g[u] = pos4[(kbase + t0 + u) * 4];  // wave-uniform loads
    #pragma unroll
    for (int u = 0; u < 8; ++u) {
      float d2 = dist2(qp, g[u]);
      sd[cnt * 1024 + tid] = d2;                       // unconditional (slot <= 10 valid)
      cnt += (d2 < thrF) ? 1 : 0;                      // branchless accept
    }
    if (__any(cnt >= TRIG3)) { FLUSH3(); }
  }
  FLUSH3();

  md[wv][lane][0] = t0v;
  md[wv][lane][1] = t1v;
  md[wv][lane][2] = t2v;
  md[wv][lane][3] = INF;                 // sentinel: heads may clamp at 3
  __syncthreads();

  if (tid < 64) {                        // 16-way merge of top-3 lists, take 20th
    int ql = tid;
    int h0=0,h1=0,h2=0,h3=0,h4=0,h5=0,h6=0,h7=0;
    int h8=0,h9=0,h10=0,h11=0,h12=0,h13=0,h14=0,h15=0;
    float last = INF;
    for (int r = 0; r < KNNK; ++r) {     // 48 finite values exist -> last finite
      float c0 = md[ 0][ql][h0],  c1 = md[ 1][ql][h1];
      float c2 = md[ 2][ql][h2],  c3 = md[ 3][ql][h3];
      float c4 = md[ 4][ql][h4],  c5 = md[ 5][ql][h5];
      float c6 = md[ 6][ql][h6],  c7 = md[ 7][ql][h7];
      float c8 = md[ 8][ql][h8],  c9 = md[ 9][ql][h9];
      float cA = md[10][ql][h10], cB = md[11][ql][h11];
      float cC = md[12][ql][h12], cD = md[13][ql][h13];
      float cE = md[14][ql][h14], cF = md[15][ql][h15];
      float bv = c0; int bw = 0;
      if (c1 < bv) { bv = c1; bw = 1; }
      if (c2 < bv) { bv = c2; bw = 2; }
      if (c3 < bv) { bv = c3; bw = 3; }
      if (c4 < bv) { bv = c4; bw = 4; }
      if (c5 < bv) { bv = c5; bw = 5; }
      if (c6 < bv) { bv = c6; bw = 6; }
      if (c7 < bv) { bv = c7; bw = 7; }
      if (c8 < bv) { bv = c8; bw = 8; }
      if (c9 < bv) { bv = c9; bw = 9; }
      if (cA < bv) { bv = cA; bw = 10; }
      if (cB < bv) { bv = cB; bw = 11; }
      if (cC < bv) { bv = cC; bw = 12; }
      if (cD < bv) { bv = cD; bw = 13; }
      if (cE < bv) { bv = cE; bw = 14; }
      if (cF < bv) { bv = cF; bw = 15; }
      last = bv;
      h0  += (bw==0);  h1  += (bw==1);  h2  += (bw==2);  h3  += (bw==3);
      h4  += (bw==4);  h5  += (bw==5);  h6  += (bw==6);  h7  += (bw==7);
      h8  += (bw==8);  h9  += (bw==9);  h10 += (bw==10); h11 += (bw==11);
      h12 += (bw==12); h13 += (bw==13); h14 += (bw==14); h15 += (bw==15);
    }
    tau[qg * 64 + ql] = last * 1.00001f;
  }
}

// ---------------------------------------------------------------- s1x: scalar-broadcast screen
// grid 1024 = 256 qg x 4 part-blocks; block 4 waves; wave -> part = pb*4+wv.
// LANE = QUERY (Q + tau'' + survivor COUNTER all in registers); candidates via
// wave-uniform scalar loads. Accept: fmaf(0.5,cw,-dot) <= Qt.
// Survivors -> private per-(q,part) global segment: no atomics, no LDS.
__global__ __launch_bounds__(256) void knnconv_s1x(const float4* __restrict__ pos4,
                                                   const float* __restrict__ tau,
                                                   u16* __restrict__ g1,
                                                   u16* __restrict__ gcnt) {
  const int tid  = threadIdx.x;
  const int lane = tid & 63;
  const int wv   = __builtin_amdgcn_readfirstlane(tid >> 6);   // uniform -> SGPR
  const int qg   = blockIdx.x >> 2;
  const int pb   = blockIdx.x & 3;
  const int part = pb * 4 + wv;          // 0..15, one wave owns one part
  const int q    = qg * 64 + lane;
  const float4 P = pos4[q];
  const float Qx = P.x, Qy = P.y, Qz = P.z;
  const float Qt = 0.5f * (tau[q] - P.w);
  const int cbase = part * PSZ;
  const float4* cp = pos4 + cbase;       // SGPR base -> s_load candidates
  u16* seg = g1 + (q * NSEG + part) * SCAP;
  int cnt = 0;

  #pragma unroll 1
  for (int t0 = 0; t0 < PSZ; t0 += 8) {
    float4 c[8];
    #pragma unroll
    for (int u = 0; u < 8; ++u) c[u] = cp[t0 + u];     // wave-uniform scalar loads
    #pragma unroll
    for (int u = 0; u < 8; ++u) {
      float dot = fmaf(Qx, c[u].x, fmaf(Qy, c[u].y, Qz * c[u].z));
      float lhs = fmaf(0.5f, c[u].w, -dot);            // 0.5*cw - dot
      if (lhs <= Qt) {                                 // rare (p ~ 0.5% per lane)
        if (cnt < SCAP) seg[cnt] = (u16)(cbase + t0 + u);
        ++cnt;
      }
    }
  }
  gcnt[q * NSEG + part] = (u16)min(cnt, SCAP);
}

// ---------------------------------------------------------------- s2: gather + f64 re-rank
// block = 16 queries x 16 segment-threads; keys[16][256] u64; rank-count.
__global__ __launch_bounds__(256) void knnconv_s2(const float4* __restrict__ pos4,
                                                  const u16* __restrict__ g1,
                                                  const u16* __restrict__ gcnt,
                                                  u16* __restrict__ knn_out) {
  __shared__ u64 keys[16 * 256];         // 32KB
  __shared__ int Tq[16];
  const int tid = threadIdx.x;
  const int iq = tid >> 4, s = tid & 15;
  const int q0 = blockIdx.x * 16;
  const int q = q0 + iq;

  #pragma unroll
  for (int i = 0; i < 16; ++i) keys[i * 256 + tid] = ~0ULL;
  __syncthreads();

  int off = 0, T = 0;
  #pragma unroll
  for (int j = 0; j < NSEG; ++j) {
    int cj = gcnt[q * NSEG + j];
    off += (j < s) ? cj : 0;
    T += cj;
  }
  if (s == 15) Tq[iq] = min(T, 256);
  int myc = gcnt[q * NSEG + s];
  float4 P = pos4[q];
  for (int i = 0; i < myc; ++i) {
    int pos = off + i;
    if (pos >= 256) break;               // deterministic clamp (P ~ 0)
    int cidx = (int)g1[(q * NSEG + s) * SCAP + i];
    float4 C = pos4[cidx];
    double qx = P.x, qy = P.y, qz = P.z;
    double cx = C.x, cy = C.y, cz = C.z;
    double sqq = qx * qx + qy * qy + qz * qz;
    double sqc = cx * cx + cy * cy + cz * cz;
    double dot = qx * cx + qy * cy + qz * cz;
    double d   = (sqq + sqc) - 2.0 * dot;              // exact to ~1e-16
    float df = fmaxf((float)d, 0.0f);                  // one rounding, 6e-8 rel
    keys[iq * 256 + pos] = ((u64)__builtin_bit_cast(u32, df) << 14) | (u32)cidx;
  }
  __syncthreads();

  #pragma unroll 1
  for (int t = 0; t < 16; ++t) {         // uniform per-block iteration
    int T2 = Tq[t];
    if (tid < T2) {
      u64 kj = keys[t * 256 + tid];
      const u64* row = keys + t * 256;
      int r = 0;
      for (int k = 0; k < T2; ++k) r += (row[k] < kj) ? 1 : 0;   // broadcast reads
      if (r < KNNK)
        knn_out[(q0 + t) * KNNK + r] = (u16)(kj & 0x3FFFu);
    }
  }
}

// ---------------------------------------------------------------- W1/W2 -> pre-swizzled bf16 (one-shot)
__global__ __launch_bounds__(256) void knnconv_wprep(const float* __restrict__ W1,
                                                     const float* __restrict__ W2,
                                                     u16* __restrict__ w1bf,
                                                     u16* __restrict__ w2bf) {
  int b = blockIdx.x;
  if (b < 128) {
    int e = b * 256 + threadIdx.x;       // 32768 entries
    int n = e >> 7, kk = e & 127;
    float v;
    if (n < 128) v = W1[(128 + kk) * 128 + n];                              // W1d
    else { int n2 = n - 128; v = W1[kk * 128 + n2] - W1[(128 + kk) * 128 + n2]; }  // W1c-W1d
    w1bf[(n * 256 + ((kk * 2) ^ ((n & 7) << 4))) >> 1] = f2bf(v);
  } else {
    int e = (b - 128) * 256 + threadIdx.x;   // 16384 entries
    int n = e >> 7, kk = e & 127;
    w2bf[(n * 256 + ((kk * 2) ^ ((n & 7) << 4))) >> 1] = f2bf(W2[kk * 128 + n]);
  }
}

// ---------------------------------------------------------------- precompute a = f@W1d (bf16), c = f@(W1c-W1d)+b1 (f32)
__global__ __launch_bounds__(256) void knnconv_prec(const float* __restrict__ feat,
                                                    const u16* __restrict__ w1bf,
                                                    const float* __restrict__ b1,
                                                    u16* __restrict__ a_out,
                                                    float* __restrict__ c_out) {
  __shared__ char sW[65536];   // WT[n=256][k=128] bf16, pre-swizzled (linear copy)
  __shared__ char sF[16384];   // FA[m=64][k=128] bf16, XOR-swizzled
  const int tid = threadIdx.x;
  { // linear coalesced copy of pre-swizzled W1-combined
    const uint4* src = (const uint4*)w1bf;
    uint4* dst = (uint4*)sW;
    #pragma unroll
    for (int r = 0; r < 16; ++r) dst[r * 256 + tid] = src[r * 256 + tid];
  }
  { // stage FA rows (bf16x8 per lane)
    int sub = tid & 15, r0 = tid >> 4;
    int m0 = blockIdx.x * 64;
    for (int rr = 0; rr < 4; ++rr) {
      int r = r0 + rr * 16;
      const float* src = feat + (m0 + r) * 128 + sub * 8;
      float4 v0 = *(const float4*)src;
      float4 v1 = *(const float4*)(src + 4);
      u32 p0 = (u32)f2bf(v0.x) | ((u32)f2bf(v0.y) << 16);
      u32 p1 = (u32)f2bf(v0.z) | ((u32)f2bf(v0.w) << 16);
      u32 p2 = (u32)f2bf(v1.x) | ((u32)f2bf(v1.y) << 16);
      u32 p3 = (u32)f2bf(v1.z) | ((u32)f2bf(v1.w) << 16);
      *(uint4*)(sF + r * 256 + ((sub * 16) ^ ((r & 7) << 4))) = make_uint4(p0, p1, p2, p3);
    }
  }
  __syncthreads();
  const int lane = tid & 63, wv = tid >> 6;
  const int l15 = lane & 15, l4 = lane >> 4;
  f32x4 acc[4][4];
  #pragma unroll
  for (int a = 0; a < 4; ++a)
    #pragma unroll
    for (int b = 0; b < 4; ++b) acc[a][b] = (f32x4){0.f, 0.f, 0.f, 0.f};
  #pragma unroll
  for (int kk = 0; kk < 4; ++kk) {
    int kb = kk * 64 + l4 * 16;
    s16x8 af[4], bfr[4];
    #pragma unroll
    for (int mt = 0; mt < 4; ++mt) {
      int row = mt * 16 + l15;
      af[mt] = *(const s16x8*)(sF + row * 256 + (kb ^ ((row & 7) << 4)));
    }
    #pragma unroll
    for (int nt = 0; nt < 4; ++nt) {
      int n = (wv * 4 + nt) * 16 + l15;
      bfr[nt] = *(const s16x8*)(sW + n * 256 + (kb ^ ((n & 7) << 4)));
    }
    #pragma unroll
    for (int mt = 0; mt < 4; ++mt)
      #pragma unroll
      for (int nt = 0; nt < 4; ++nt)
        acc[mt][nt] = MFMA_BF16(af[mt], bfr[nt], acc[mt][nt], 0, 0, 0);
  }
  int m0 = blockIdx.x * 64;
  #pragma unroll
  for (int nt = 0; nt < 4; ++nt) {
    int n = (wv * 4 + nt) * 16 + l15;
    float bias = (n >= 128) ? b1[n - 128] : 0.0f;
    #pragma unroll
    for (int mt = 0; mt < 4; ++mt)
      #pragma unroll
      for (int r = 0; r < 4; ++r) {
        int m = m0 + mt * 16 + l4 * 4 + r;    // C/D: row=(l>>4)*4+reg, col=l&15
        float v = acc[mt][nt][r];
        if (n < 128) a_out[m * 128 + n] = f2bf(v);
        else         c_out[m * 128 + (n - 128)] = v + bias;
      }
  }
}

// ---------------------------------------------------------------- fused gather + relu + GEMM2 + max
__global__ __launch_bounds__(256) void knnconv_conv(const u16* __restrict__ knn,
                                                    const u16* __restrict__ a_in,
                                                    const float* __restrict__ c_in,
                                                    const u16* __restrict__ w2bf,
                                                    const float* __restrict__ b2,
                                                    float* __restrict__ out) {
  __shared__ char lds[77824];     // [0,40960): A / H2  | [40960,73728): W2T | [73728,77824): c rows
  char* sA = lds;
  char* sW = lds + 40960;
  char* sC = lds + 73728;
  const int tid = threadIdx.x;
  const int q0 = blockIdx.x * 8;

  { // stage c rows for the 8 queries
    int row = tid >> 5, ch4 = (tid & 31) * 4;
    *(float4*)(sC + (row * 128 + ch4) * 4) = *(const float4*)(c_in + (q0 + row) * 128 + ch4);
  }
  __syncthreads();
  { // copy pre-swizzled W2 bf16 (linear copy; layout already swizzled)
    const uint4* src = (const uint4*)w2bf;
    uint4* dst = (uint4*)sW;
    #pragma unroll
    for (int r = 0; r < 8; ++r) dst[r * 256 + tid] = src[r * 256 + tid];
  }
  { // stage A: row r = (query il, neighbor ke): relu(a[idx] + c[il]) -> bf16, swizzled
    int sub = tid & 15, rr = tid >> 4;
    for (int p = 0; p < 10; ++p) {
      int r = p * 16 + rr;
      int il = r / 20;
      int ke = r - il * 20;
      int idx = (int)knn[(q0 + il) * KNNK + ke];
      uint4 av = *(const uint4*)(a_in + idx * 128 + sub * 8);
      float4 c0 = *(const float4*)(sC + (il * 128 + sub * 8) * 4);
      float4 c1 = *(const float4*)(sC + (il * 128 + sub * 8 + 4) * 4);
      float h0 = fmaxf(bf2f((u16)(av.x & 0xFFFF)) + c0.x, 0.f);
      float h1 = fmaxf(bf2f((u16)(av.x >> 16))    + c0.y, 0.f);
      float h2 = fmaxf(bf2f((u16)(av.y & 0xFFFF)) + c0.z, 0.f);
      float h3 = fmaxf(bf2f((u16)(av.y >> 16))    + c0.w, 0.f);
      float h4 = fmaxf(bf2f((u16)(av.z & 0xFFFF)) + c1.x, 0.f);
      float h5 = fmaxf(bf2f((u16)(av.z >> 16))    + c1.y, 0.f);
      float h6 = fmaxf(bf2f((u16)(av.w & 0xFFFF)) + c1.z, 0.f);
      float h7 = fmaxf(bf2f((u16)(av.w >> 16))    + c1.w, 0.f);
      u32 p0 = (u32)f2bf(h0) | ((u32)f2bf(h1) << 16);
      u32 p1 = (u32)f2bf(h2) | ((u32)f2bf(h3) << 16);
      u32 p2 = (u32)f2bf(h4) | ((u32)f2bf(h5) << 16);
      u32 p3 = (u32)f2bf(h6) | ((u32)f2bf(h7) << 16);
      *(uint4*)(sA + r * 256 + ((sub * 16) ^ ((r & 7) << 4))) = make_uint4(p0, p1, p2, p3);
    }
  }
  __syncthreads();
  const int lane = tid & 63, wv = tid >> 6;
  const int l15 = lane & 15, l4 = lane >> 4;
  f32x4 acc[10][2];
  #pragma unroll
  for (int mt = 0; mt < 10; ++mt) { acc[mt][0] = (f32x4){0,0,0,0}; acc[mt][1] = (f32x4){0,0,0,0}; }
  #pragma unroll
  for (int kk = 0; kk < 4; ++kk) {
    int kb = kk * 64 + l4 * 16;
    s16x8 b0, b1r;
    { int n = (wv * 2 + 0) * 16 + l15; b0  = *(const s16x8*)(sW + n * 256 + (kb ^ ((n & 7) << 4))); }
    { int n = (wv * 2 + 1) * 16 + l15; b1r = *(const s16x8*)(sW + n * 256 + (kb ^ ((n & 7) << 4))); }
    #pragma unroll
    for (int mt = 0; mt < 10; ++mt) {
      int row = mt * 16 + l15;
      s16x8 a = *(const s16x8*)(sA + row * 256 + (kb ^ ((row & 7) << 4)));
      acc[mt][0] = MFMA_BF16(a, b0,  acc[mt][0], 0, 0, 0);
      acc[mt][1] = MFMA_BF16(a, b1r, acc[mt][1], 0, 0, 0);
    }
  }
  __syncthreads();              // all waves done reading A before H2 overwrite
  #pragma unroll
  for (int mt = 0; mt < 10; ++mt)
    #pragma unroll
    for (int nt = 0; nt < 2; ++nt) {
      int n = (wv * 2 + nt) * 16 + l15;
      #pragma unroll
      for (int r = 0; r < 4; ++r) {
        int row = mt * 16 + l4 * 4 + r;
        *(u16*)(sA + row * 256 + n * 2) = f2bf(acc[mt][nt][r]);  // H2, plain layout
      }
    }
  __syncthreads();
  { // max over 20 neighbors + b2
    int ch = tid & 127, g = tid >> 7;
    float bias = b2[ch];
    for (int pp = 0; pp < 4; ++pp) {
      int qq = pp * 2 + g;
      float mx = -__builtin_inff();
      #pragma unroll
      for (int e = 0; e < KNNK; ++e)
        mx = fmaxf(mx, bf2f(*(const u16*)(sA + (qq * 20 + e) * 256 + ch * 2)));
      out[(q0 + qq) * 128 + ch] = mx + bias;
    }
  }
}

// ---------------------------------------------------------------- launch
extern "C" void kernel_launch(void* const* d_in, const int* in_sizes, int n_in,
                              void* d_out, int out_size, void* d_ws, size_t ws_size,
                              hipStream_t stream) {
  const float* pos  = (const float*)d_in[0];
  const float* feat = (const float*)d_in[1];
  const float* W1   = (const float*)d_in[2];
  const float* b1   = (const float*)d_in[3];
  const float* W2   = (const float*)d_in[4];
  const float* b2   = (const float*)d_in[5];
  float* out = (float*)d_out;
  char* ws = (char*)d_ws;
  // ws layout (aliases noted):
  //  [0,256K)              pos4 (prep..s2)        -> w1bf 64KB + w2bf 32KB (wprep..conv)
  //  [256K,917504)         knn u16 (s2..conv)
  //  [917504,13500416)     g1 [16384][16][24] u16 (s1x..s2) -> a_buf 4MB + c_buf 8MB (prec..conv)
  //  [13500416,14024704)   gcnt [16384][16] u16 (s1x..s2)
  //  [14024704,14090240)   tau [16384] f32 (s0..s1x)
  float4* pos4  = (float4*)ws;
  u16*    w1bf  = (u16*)ws;
  u16*    w2bf  = (u16*)(ws + 65536);
  u16*    knn   = (u16*)(ws + 262144);
  u16*    g1    = (u16*)(ws + 917504);
  u16*    a_buf = (u16*)(ws + 917504);
  float*  c_buf = (float*)(ws + 5111808);
  u16*    gcnt  = (u16*)(ws + 13500416);
  float*  tau   = (float*)(ws + 14024704);
  if (ws_size < 14090240) return;   // insufficient scratch (would corrupt)

  knnconv_prep<<<64, 256, 0, stream>>>(pos, pos4);
  knnconv_s0<<<256, 1024, 0, stream>>>(pos4, tau);
  knnconv_s1x<<<1024, 256, 0, stream>>>(pos4, tau, g1, gcnt);
  knnconv_s2<<<1024, 256, 0, stream>>>(pos4, g1, gcnt, knn);
  knnconv_wprep<<<192, 256, 0, stream>>>(W1, W2, w1bf, w2bf);          // overwrites pos4 (dead)
  knnconv_prec<<<256, 256, 0, stream>>>(feat, w1bf, b1, a_buf, c_buf); // overwrites g1 (dead)
  knnconv_conv<<<2048, 256, 0, stream>>>(knn, a_buf, c_buf, w2bf, b2, out);
}

// Round 16
// 221.613 us; speedup vs baseline: 1.5264x; 1.0223x over previous
//
#include <hip/hip_runtime.h>

typedef unsigned short u16;
typedef unsigned int   u32;
typedef unsigned long long u64;
typedef short s16x8 __attribute__((ext_vector_type(8)));   // 8 x bf16 bits (4 VGPRs)
typedef float f32x4 __attribute__((ext_vector_type(4)));   // MFMA accumulator

#define NPTS   16384
#define KNNK   20
#define SLOTS3 12      // s0 stack slots (trigger 4, growth <= 8 => max 11)
#define TRIG3  4
#define NSEG   16      // s1x candidate parts per query
#define PSZ    1024    // candidates per part
#define SCAP   24      // survivor cap per (query, part)  [E~5; P(overflow) ~1e-4 total]

#define MFMA_BF16 __builtin_amdgcn_mfma_f32_16x16x32_bf16

__device__ __forceinline__ u16 f2bf(float x) {
  u32 u = __builtin_bit_cast(u32, x);
  u32 r = (u + 0x7FFFu + ((u >> 16) & 1u)) >> 16;   // RNE
  return (u16)r;
}
__device__ __forceinline__ float bf2f(u16 b) {
  u32 u = ((u32)b) << 16;
  return __builtin_bit_cast(float, u);
}
__device__ __forceinline__ float dist2(float4 qp, float4 cd) {
  float dot = fmaf(qp.x, cd.x, fmaf(qp.y, cd.y, qp.z * cd.z));
  return fmaf(-2.0f, dot, qp.w + cd.w);
}

// ---------------------------------------------------------------- prep: pos4 = (x,y,z,|p|^2)
__global__ __launch_bounds__(256) void knnconv_prep(const float* __restrict__ pos,
                                                    float4* __restrict__ pos4) {
  int i = blockIdx.x * 256 + threadIdx.x;
  float x = pos[i * 3 + 0], y = pos[i * 3 + 1], z = pos[i * 3 + 2];
  float sq = (x * x + y * y) + z * z;    // f32 screen only; f64 re-rank decides final set
  pos4[i] = make_float4(x, y, z, sq);
}

// ---------------------------------------------------------------- s0: sample threshold
// grid 256 (query-group); block 1024 = 16 waves. lane = query; wave wv scans 256
// samples (every 4th point). Each wave keeps only TOP-3 (lazy stack, 3-stage
// pair-carry ladder). tau = 20th smallest of the 48-value union: provable
// superset bound (>=20 full points within tau).
__global__ __launch_bounds__(1024) void knnconv_s0(const float4* __restrict__ pos4,
                                                   float* __restrict__ tau) {
  __shared__ float sd[SLOTS3 * 1024];    // 48KB per-lane stacks
  __shared__ float md[16][64][4];        // 16KB sorted top-3 + INF sentinel
  const int tid  = threadIdx.x;
  const int lane = tid & 63;
  const int wv   = __builtin_amdgcn_readfirstlane(tid >> 6);   // 0..15, uniform
  const int qg   = blockIdx.x;
  const int q    = qg * 64 + lane;
  const float4 qp = pos4[q];
  const float INF = __builtin_inff();

  float t0v = INF, t1v = INF, t2v = INF; // sorted top-3 in registers
  float thrF = INF;
  int cnt = 0;
  const int kbase = wv * 256;            // sample index base (sample i -> point 4i)

#define FLUSH3()                                                      \
  { _Pragma("unroll 1")                                               \
    for (int e = 0; e < SLOTS3; e += 2) {                             \
      if (!__any(e < cnt)) break;                                     \
      float lo = (e     < cnt) ? sd[e * 1024 + tid]       : INF;      \
      float hi = (e + 1 < cnt) ? sd[(e + 1) * 1024 + tid] : INF;      \
      float a_ = fminf(lo, hi), b_ = fmaxf(lo, hi);                   \
      lo = a_; hi = b_;                                               \
      { float m = fminf(lo, t0v), x = fmaxf(lo, t0v);                 \
        t0v = m; lo = fminf(x, hi); hi = fmaxf(x, hi); }              \
      { float m = fminf(lo, t1v), x = fmaxf(lo, t1v);                 \
        t1v = m; lo = fminf(x, hi); hi = fmaxf(x, hi); }              \
      t2v = fminf(lo, t2v);                                           \
    }                                                                 \
    thrF = t2v;                                                       \
    cnt = 0; }

  for (int t0 = 0; t0 < 256; t0 += 8) {
    float4 g[8];
    #pragma unroll
    for (int u = 0; u < 8; ++u) g[u] = pos4[(kbase + t0 + u) * 4];  // wave-uniform loads
    #pragma unroll
    for (int u = 0; u < 8; ++u) {
      float d2 = dist2(qp, g[u]);
      sd[cnt * 1024 + tid] = d2;                       // unconditional (slot <= 10 valid)
      cnt += (d2 < thrF) ? 1 : 0;                      // branchless accept
    }
    if (__any(cnt >= TRIG3)) { FLUSH3(); }
  }
  FLUSH3();

  md[wv][lane][0] = t0v;
  md[wv][lane][1] = t1v;
  md[wv][lane][2] = t2v;
  md[wv][lane][3] = INF;                 // sentinel: heads may clamp at 3
  __syncthreads();

  if (tid < 64) {                        // 16-way merge of top-3 lists, take 20th
    int ql = tid;
    int h0=0,h1=0,h2=0,h3=0,h4=0,h5=0,h6=0,h7=0;
    int h8=0,h9=0,h10=0,h11=0,h12=0,h13=0,h14=0,h15=0;
    float last = INF;
    for (int r = 0; r < KNNK; ++r) {     // 48 finite values exist -> last finite
      float c0 = md[ 0][ql][h0],  c1 = md[ 1][ql][h1];
      float c2 = md[ 2][ql][h2],  c3 = md[ 3][ql][h3];
      float c4 = md[ 4][ql][h4],  c5 = md[ 5][ql][h5];
      float c6 = md[ 6][ql][h6],  c7 = md[ 7][ql][h7];
      float c8 = md[ 8][ql][h8],  c9 = md[ 9][ql][h9];
      float cA = md[10][ql][h10], cB = md[11][ql][h11];
      float cC = md[12][ql][h12], cD = md[13][ql][h13];
      float cE = md[14][ql][h14], cF = md[15][ql][h15];
      float bv = c0; int bw = 0;
      if (c1 < bv) { bv = c1; bw = 1; }
      if (c2 < bv) { bv = c2; bw = 2; }
      if (c3 < bv) { bv = c3; bw = 3; }
      if (c4 < bv) { bv = c4; bw = 4; }
      if (c5 < bv) { bv = c5; bw = 5; }
      if (c6 < bv) { bv = c6; bw = 6; }
      if (c7 < bv) { bv = c7; bw = 7; }
      if (c8 < bv) { bv = c8; bw = 8; }
      if (c9 < bv) { bv = c9; bw = 9; }
      if (cA < bv) { bv = cA; bw = 10; }
      if (cB < bv) { bv = cB; bw = 11; }
      if (cC < bv) { bv = cC; bw = 12; }
      if (cD < bv) { bv = cD; bw = 13; }
      if (cE < bv) { bv = cE; bw = 14; }
      if (cF < bv) { bv = cF; bw = 15; }
      last = bv;
      h0  += (bw==0);  h1  += (bw==1);  h2  += (bw==2);  h3  += (bw==3);
      h4  += (bw==4);  h5  += (bw==5);  h6  += (bw==6);  h7  += (bw==7);
      h8  += (bw==8);  h9  += (bw==9);  h10 += (bw==10); h11 += (bw==11);
      h12 += (bw==12); h13 += (bw==13); h14 += (bw==14); h15 += (bw==15);
    }
    tau[qg * 64 + ql] = last * 1.00001f;
  }
}

// ---------------------------------------------------------------- s1x: scalar-broadcast screen
// grid 1024 = 256 qg x 4 part-blocks; block 4 waves; wave -> part = pb*4+wv.
// LANE = QUERY; candidates via wave-uniform scalar loads, DEPTH-2 SOFTWARE
// PIPELINE (cA/cB named register batches): each batch's s_waitcnt is covered by
// the other batch's 48-VALU compute. Survivors -> private per-(q,part) segment.
__global__ __launch_bounds__(256) void knnconv_s1x(const float4* __restrict__ pos4,
                                                   const float* __restrict__ tau,
                                                   u16* __restrict__ g1,
                                                   u16* __restrict__ gcnt) {
  const int tid  = threadIdx.x;
  const int lane = tid & 63;
  const int wv   = __builtin_amdgcn_readfirstlane(tid >> 6);   // uniform -> SGPR
  const int qg   = blockIdx.x >> 2;
  const int pb   = blockIdx.x & 3;
  const int part = pb * 4 + wv;          // 0..15, one wave owns one part
  const int q    = qg * 64 + lane;
  const float4 P = pos4[q];
  const float Qx = P.x, Qy = P.y, Qz = P.z;
  const float Qt = 0.5f * (tau[q] - P.w);
  const int cbase = part * PSZ;
  const float4* cp = pos4 + cbase;       // SGPR base -> s_load candidates
  u16* seg = g1 + (q * NSEG + part) * SCAP;
  int cnt = 0;

#define S1LOAD(dst, base)                                             \
  { _Pragma("unroll")                                                 \
    for (int u = 0; u < 8; ++u) dst[u] = cp[(base) + u]; }

#define S1PROC(c, base)                                               \
  { _Pragma("unroll")                                                 \
    for (int u = 0; u < 8; ++u) {                                     \
      float dot = fmaf(Qx, c[u].x, fmaf(Qy, c[u].y, Qz * c[u].z));    \
      float lhs = fmaf(0.5f, c[u].w, -dot);                           \
      if (lhs <= Qt) {                                                \
        if (cnt < SCAP) seg[cnt] = (u16)(cbase + (base) + u);         \
        ++cnt;                                                        \
      }                                                               \
    } }

  float4 cA[8], cB[8];
  S1LOAD(cA, 0);
  #pragma unroll 1
  for (int t0 = 0; t0 < PSZ; t0 += 16) {
    S1LOAD(cB, t0 + 8);                  // issue B loads before A compute
    S1PROC(cA, t0);
    S1LOAD(cA, (t0 + 16) & (PSZ - 1));   // wraps to 0 on final iter (in-bounds, discarded)
    S1PROC(cB, t0 + 8);
  }
  gcnt[q * NSEG + part] = (u16)min(cnt, SCAP);
}

// ---------------------------------------------------------------- s2: gather + f64 re-rank
// block = 16 queries x 16 segment-threads; keys[16][256] u64; rank-count.
__global__ __launch_bounds__(256) void knnconv_s2(const float4* __restrict__ pos4,
                                                  const u16* __restrict__ g1,
                                                  const u16* __restrict__ gcnt,
                                                  u16* __restrict__ knn_out) {
  __shared__ u64 keys[16 * 256];         // 32KB
  __shared__ int Tq[16];
  const int tid = threadIdx.x;
  const int iq = tid >> 4, s = tid & 15;
  const int q0 = blockIdx.x * 16;
  const int q = q0 + iq;

  #pragma unroll
  for (int i = 0; i < 16; ++i) keys[i * 256 + tid] = ~0ULL;
  __syncthreads();

  int off = 0, T = 0;
  #pragma unroll
  for (int j = 0; j < NSEG; ++j) {
    int cj = gcnt[q * NSEG + j];
    off += (j < s) ? cj : 0;
    T += cj;
  }
  if (s == 15) Tq[iq] = min(T, 256);
  int myc = gcnt[q * NSEG + s];
  float4 P = pos4[q];
  for (int i = 0; i < myc; ++i) {
    int pos = off + i;
    if (pos >= 256) break;               // deterministic clamp (P ~ 0)
    int cidx = (int)g1[(q * NSEG + s) * SCAP + i];
    float4 C = pos4[cidx];
    double qx = P.x, qy = P.y, qz = P.z;
    double cx = C.x, cy = C.y, cz = C.z;
    double sqq = qx * qx + qy * qy + qz * qz;
    double sqc = cx * cx + cy * cy + cz * cz;
    double dot = qx * cx + qy * cy + qz * cz;
    double d   = (sqq + sqc) - 2.0 * dot;              // exact to ~1e-16
    float df = fmaxf((float)d, 0.0f);                  // one rounding, 6e-8 rel
    keys[iq * 256 + pos] = ((u64)__builtin_bit_cast(u32, df) << 14) | (u32)cidx;
  }
  __syncthreads();

  #pragma unroll 1
  for (int t = 0; t < 16; ++t) {         // uniform per-block iteration
    int T2 = Tq[t];
    if (tid < T2) {
      u64 kj = keys[t * 256 + tid];
      const u64* row = keys + t * 256;
      int r = 0;
      for (int k = 0; k < T2; ++k) r += (row[k] < kj) ? 1 : 0;   // broadcast reads
      if (r < KNNK)
        knn_out[(q0 + t) * KNNK + r] = (u16)(kj & 0x3FFFu);
    }
  }
}

// ---------------------------------------------------------------- W1/W2 -> pre-swizzled bf16 (one-shot)
__global__ __launch_bounds__(256) void knnconv_wprep(const float* __restrict__ W1,
                                                     const float* __restrict__ W2,
                                                     u16* __restrict__ w1bf,
                                                     u16* __restrict__ w2bf) {
  int b = blockIdx.x;
  if (b < 128) {
    int e = b * 256 + threadIdx.x;       // 32768 entries
    int n = e >> 7, kk = e & 127;
    float v;
    if (n < 128) v = W1[(128 + kk) * 128 + n];                              // W1d
    else { int n2 = n - 128; v = W1[kk * 128 + n2] - W1[(128 + kk) * 128 + n2]; }  // W1c-W1d
    w1bf[(n * 256 + ((kk * 2) ^ ((n & 7) << 4))) >> 1] = f2bf(v);
  } else {
    int e = (b - 128) * 256 + threadIdx.x;   // 16384 entries
    int n = e >> 7, kk = e & 127;
    w2bf[(n * 256 + ((kk * 2) ^ ((n & 7) << 4))) >> 1] = f2bf(W2[kk * 128 + n]);
  }
}

// ---------------------------------------------------------------- precompute a = f@W1d (bf16), c = f@(W1c-W1d)+b1 (f32)
__global__ __launch_bounds__(256) void knnconv_prec(const float* __restrict__ feat,
                                                    const u16* __restrict__ w1bf,
                                                    const float* __restrict__ b1,
                                                    u16* __restrict__ a_out,
                                                    float* __restrict__ c_out) {
  __shared__ char sW[65536];   // WT[n=256][k=128] bf16, pre-swizzled (linear copy)
  __shared__ char sF[16384];   // FA[m=64][k=128] bf16, XOR-swizzled
  const int tid = threadIdx.x;
  { // linear coalesced copy of pre-swizzled W1-combined
    const uint4* src = (const uint4*)w1bf;
    uint4* dst = (uint4*)sW;
    #pragma unroll
    for (int r = 0; r < 16; ++r) dst[r * 256 + tid] = src[r * 256 + tid];
  }
  { // stage FA rows (bf16x8 per lane)
    int sub = tid & 15, r0 = tid >> 4;
    int m0 = blockIdx.x * 64;
    for (int rr = 0; rr < 4; ++rr) {
      int r = r0 + rr * 16;
      const float* src = feat + (m0 + r) * 128 + sub * 8;
      float4 v0 = *(const float4*)src;
      float4 v1 = *(const float4*)(src + 4);
      u32 p0 = (u32)f2bf(v0.x) | ((u32)f2bf(v0.y) << 16);
      u32 p1 = (u32)f2bf(v0.z) | ((u32)f2bf(v0.w) << 16);
      u32 p2 = (u32)f2bf(v1.x) | ((u32)f2bf(v1.y) << 16);
      u32 p3 = (u32)f2bf(v1.z) | ((u32)f2bf(v1.w) << 16);
      *(uint4*)(sF + r * 256 + ((sub * 16) ^ ((r & 7) << 4))) = make_uint4(p0, p1, p2, p3);
    }
  }
  __syncthreads();
  const int lane = tid & 63, wv = tid >> 6;
  const int l15 = lane & 15, l4 = lane >> 4;
  f32x4 acc[4][4];
  #pragma unroll
  for (int a = 0; a < 4; ++a)
    #pragma unroll
    for (int b = 0; b < 4; ++b) acc[a][b] = (f32x4){0.f, 0.f, 0.f, 0.f};
  #pragma unroll
  for (int kk = 0; kk < 4; ++kk) {
    int kb = kk * 64 + l4 * 16;
    s16x8 af[4], bfr[4];
    #pragma unroll
    for (int mt = 0; mt < 4; ++mt) {
      int row = mt * 16 + l15;
      af[mt] = *(const s16x8*)(sF + row * 256 + (kb ^ ((row & 7) << 4)));
    }
    #pragma unroll
    for (int nt = 0; nt < 4; ++nt) {
      int n = (wv * 4 + nt) * 16 + l15;
      bfr[nt] = *(const s16x8*)(sW + n * 256 + (kb ^ ((n & 7) << 4)));
    }
    #pragma unroll
    for (int mt = 0; mt < 4; ++mt)
      #pragma unroll
      for (int nt = 0; nt < 4; ++nt)
        acc[mt][nt] = MFMA_BF16(af[mt], bfr[nt], acc[mt][nt], 0, 0, 0);
  }
  int m0 = blockIdx.x * 64;
  #pragma unroll
  for (int nt = 0; nt < 4; ++nt) {
    int n = (wv * 4 + nt) * 16 + l15;
    float bias = (n >= 128) ? b1[n - 128] : 0.0f;
    #pragma unroll
    for (int mt = 0; mt < 4; ++mt)
      #pragma unroll
      for (int r = 0; r < 4; ++r) {
        int m = m0 + mt * 16 + l4 * 4 + r;    // C/D: row=(l>>4)*4+reg, col=l&15
        float v = acc[mt][nt][r];
        if (n < 128) a_out[m * 128 + n] = f2bf(v);
        else         c_out[m * 128 + (n - 128)] = v + bias;
      }
  }
}

// ---------------------------------------------------------------- fused gather + relu + GEMM2 + max
__global__ __launch_bounds__(256) void knnconv_conv(const u16* __restrict__ knn,
                                                    const u16* __restrict__ a_in,
                                                    const float* __restrict__ c_in,
                                                    const u16* __restrict__ w2bf,
                                                    const float* __restrict__ b2,
                                                    float* __restrict__ out) {
  __shared__ char lds[77824];     // [0,40960): A / H2  | [40960,73728): W2T | [73728,77824): c rows
  char* sA = lds;
  char* sW = lds + 40960;
  char* sC = lds + 73728;
  const int tid = threadIdx.x;
  const int q0 = blockIdx.x * 8;

  { // stage c rows for the 8 queries
    int row = tid >> 5, ch4 = (tid & 31) * 4;
    *(float4*)(sC + (row * 128 + ch4) * 4) = *(const float4*)(c_in + (q0 + row) * 128 + ch4);
  }
  __syncthreads();
  { // copy pre-swizzled W2 bf16 (linear copy; layout already swizzled)
    const uint4* src = (const uint4*)w2bf;
    uint4* dst = (uint4*)sW;
    #pragma unroll
    for (int r = 0; r < 8; ++r) dst[r * 256 + tid] = src[r * 256 + tid];
  }
  { // stage A: row r = (query il, neighbor ke): relu(a[idx] + c[il]) -> bf16, swizzled
    int sub = tid & 15, rr = tid >> 4;
    for (int p = 0; p < 10; ++p) {
      int r = p * 16 + rr;
      int il = r / 20;
      int ke = r - il * 20;
      int idx = (int)knn[(q0 + il) * KNNK + ke];
      uint4 av = *(const uint4*)(a_in + idx * 128 + sub * 8);
      float4 c0 = *(const float4*)(sC + (il * 128 + sub * 8) * 4);
      float4 c1 = *(const float4*)(sC + (il * 128 + sub * 8 + 4) * 4);
      float h0 = fmaxf(bf2f((u16)(av.x & 0xFFFF)) + c0.x, 0.f);
      float h1 = fmaxf(bf2f((u16)(av.x >> 16))    + c0.y, 0.f);
      float h2 = fmaxf(bf2f((u16)(av.y & 0xFFFF)) + c0.z, 0.f);
      float h3 = fmaxf(bf2f((u16)(av.y >> 16))    + c0.w, 0.f);
      float h4 = fmaxf(bf2f((u16)(av.z & 0xFFFF)) + c1.x, 0.f);
      float h5 = fmaxf(bf2f((u16)(av.z >> 16))    + c1.y, 0.f);
      float h6 = fmaxf(bf2f((u16)(av.w & 0xFFFF)) + c1.z, 0.f);
      float h7 = fmaxf(bf2f((u16)(av.w >> 16))    + c1.w, 0.f);
      u32 p0 = (u32)f2bf(h0) | ((u32)f2bf(h1) << 16);
      u32 p1 = (u32)f2bf(h2) | ((u32)f2bf(h3) << 16);
      u32 p2 = (u32)f2bf(h4) | ((u32)f2bf(h5) << 16);
      u32 p3 = (u32)f2bf(h6) | ((u32)f2bf(h7) << 16);
      *(uint4*)(sA + r * 256 + ((sub * 16) ^ ((r & 7) << 4))) = make_uint4(p0, p1, p2, p3);
    }
  }
  __syncthreads();
  const int lane = tid & 63, wv = tid >> 6;
  const int l15 = lane & 15, l4 = lane >> 4;
  f32x4 acc[10][2];
  #pragma unroll
  for (int mt = 0; mt < 10; ++mt) { acc[mt][0] = (f32x4){0,0,0,0}; acc[mt][1] = (f32x4){0,0,0,0}; }
  #pragma unroll
  for (int kk = 0; kk < 4; ++kk) {
    int kb = kk * 64 + l4 * 16;
    s16x8 b0, b1r;
    { int n = (wv * 2 + 0) * 16 + l15; b0  = *(const s16x8*)(sW + n * 256 + (kb ^ ((n & 7) << 4))); }
    { int n = (wv * 2 + 1) * 16 + l15; b1r = *(const s16x8*)(sW + n * 256 + (kb ^ ((n & 7) << 4))); }
    #pragma unroll
    for (int mt = 0; mt < 10; ++mt) {
      int row = mt * 16 + l15;
      s16x8 a = *(const s16x8*)(sA + row * 256 + (kb ^ ((row & 7) << 4)));
      acc[mt][0] = MFMA_BF16(a, b0,  acc[mt][0], 0, 0, 0);
      acc[mt][1] = MFMA_BF16(a, b1r, acc[mt][1], 0, 0, 0);
    }
  }
  __syncthreads();              // all waves done reading A before H2 overwrite
  #pragma unroll
  for (int mt = 0; mt < 10; ++mt)
    #pragma unroll
    for (int nt = 0; nt < 2; ++nt) {
      int n = (wv * 2 + nt) * 16 + l15;
      #pragma unroll
      for (int r = 0; r < 4; ++r) {
        int row = mt * 16 + l4 * 4 + r;
        *(u16*)(sA + row * 256 + n * 2) = f2bf(acc[mt][nt][r]);  // H2, plain layout
      }
    }
  __syncthreads();
  { // max over 20 neighbors + b2
    int ch = tid & 127, g = tid >> 7;
    float bias = b2[ch];
    for (int pp = 0; pp < 4; ++pp) {
      int qq = pp * 2 + g;
      float mx = -__builtin_inff();
      #pragma unroll
      for (int e = 0; e < KNNK; ++e)
        mx = fmaxf(mx, bf2f(*(const u16*)(sA + (qq * 20 + e) * 256 + ch * 2)));
      out[(q0 + qq) * 128 + ch] = mx + bias;
    }
  }
}

// ---------------------------------------------------------------- launch
extern "C" void kernel_launch(void* const* d_in, const int* in_sizes, int n_in,
                              void* d_out, int out_size, void* d_ws, size_t ws_size,
                              hipStream_t stream) {
  const float* pos  = (const float*)d_in[0];
  const float* feat = (const float*)d_in[1];
  const float* W1   = (const float*)d_in[2];
  const float* b1   = (const float*)d_in[3];
  const float* W2   = (const float*)d_in[4];
  const float* b2   = (const float*)d_in[5];
  float* out = (float*)d_out;
  char* ws = (char*)d_ws;
  // ws layout (aliases noted):
  //  [0,256K)              pos4 (prep..s2)        -> w1bf 64KB + w2bf 32KB (wprep..conv)
  //  [256K,917504)         knn u16 (s2..conv)
  //  [917504,13500416)     g1 [16384][16][24] u16 (s1x..s2) -> a_buf 4MB + c_buf 8MB (prec..conv)
  //  [13500416,14024704)   gcnt [16384][16] u16 (s1x..s2)
  //  [14024704,14090240)   tau [16384] f32 (s0..s1x)
  float4* pos4  = (float4*)ws;
  u16*    w1bf  = (u16*)ws;
  u16*    w2bf  = (u16*)(ws + 65536);
  u16*    knn   = (u16*)(ws + 262144);
  u16*    g1    = (u16*)(ws + 917504);
  u16*    a_buf = (u16*)(ws + 917504);
  float*  c_buf = (float*)(ws + 5111808);
  u16*    gcnt  = (u16*)(ws + 13500416);
  float*  tau   = (float*)(ws + 14024704);
  if (ws_size < 14090240) return;   // insufficient scratch (would corrupt)

  knnconv_prep<<<64, 256, 0, stream>>>(pos, pos4);
  knnconv_s0<<<256, 1024, 0, stream>>>(pos4, tau);
  knnconv_s1x<<<1024, 256, 0, stream>>>(pos4, tau, g1, gcnt);
  knnconv_s2<<<1024, 256, 0, stream>>>(pos4, g1, gcnt, knn);
  knnconv_wprep<<<192, 256, 0, stream>>>(W1, W2, w1bf, w2bf);          // overwrites pos4 (dead)
  knnconv_prec<<<256, 256, 0, stream>>>(feat, w1bf, b1, a_buf, c_buf); // overwrites g1 (dead)
  knnconv_conv<<<2048, 256, 0, stream>>>(knn, a_buf, c_buf, w2bf, b2, out);
}